// Round 32
// baseline (294.814 us; speedup 1.0000x reference)
//
#include <hip/hip_runtime.h>

// GNN: 2-layer edge-coloured conv on MI355X.
// Round 32: k_gemm2g double-buffered half-panels — 24 panels x 24KB,
// LDS 2x24KB (still 3 blocks/CU); next panel staged during current panel's
// MFMA+epilogue; one barrier/panel. Everything else = round 31 (passed, 290.8us).

#define NN 50000
#define EE 800000
#define DD 128
#define HH 256
#define CC 8

typedef unsigned short u16;
typedef unsigned char u8;
typedef unsigned long long u64;
typedef __attribute__((ext_vector_type(8))) short s16x8;
typedef __attribute__((ext_vector_type(4))) float f32x4;
typedef __attribute__((ext_vector_type(2))) float f32x2;

__device__ __forceinline__ float bf2f(short u) {
  return __uint_as_float(((unsigned)(u16)u) << 16);
}
__device__ __forceinline__ u16 f2bf(float f) {
  unsigned u = __float_as_uint(f);
  u = (u + 0x7FFFu + ((u >> 16) & 1u)) >> 16;   // RNE
  return (u16)u;
}

// ---------------- prep ----------------

__global__ void k_castx(const float* __restrict__ x, u16* __restrict__ xb,
                        u8* __restrict__ xf8) {
  int i = blockIdx.x * 256 + threadIdx.x;       // 800000 exact (3125 blocks)
  const float4* xp = (const float4*)x + (size_t)i * 2;
  float4 a = xp[0], b = xp[1];
  s16x8 r;
  r[0] = f2bf(a.x); r[1] = f2bf(a.y); r[2] = f2bf(a.z); r[3] = f2bf(a.w);
  r[4] = f2bf(b.x); r[5] = f2bf(b.y); r[6] = f2bf(b.z); r[7] = f2bf(b.w);
  *(s16x8*)(xb + (size_t)i * 8) = r;
  unsigned p0 = __builtin_amdgcn_cvt_pk_fp8_f32(a.x, a.y, 0, false);
  p0 = __builtin_amdgcn_cvt_pk_fp8_f32(a.z, a.w, p0, true);
  unsigned p1 = __builtin_amdgcn_cvt_pk_fp8_f32(b.x, b.y, 0, false);
  p1 = __builtin_amdgcn_cvt_pk_fp8_f32(b.z, b.w, p1, true);
  *(uint2*)(xf8 + (size_t)i * 8) = make_uint2(p0, p1);
}

// W1c8 fp8, scaled x256
__global__ void k_wt1c8(const float* __restrict__ Wc1, unsigned* __restrict__ W) {
  int t = blockIdx.x * 256 + threadIdx.x;       // 65536 (256 blocks)
  if (t >= 65536) return;
  int half = t & 1;
  int slot = t >> 1;
  int lane = slot & 63;
  int sk = slot >> 6;
  int kkg = sk & 31, col16 = sk >> 5;
  int col = col16 * 16 + (lane & 15);
  int kb = kkg * 32 + (lane >> 4) * 8 + half * 4;
  int c = kb >> 7, f = kb & 127;
  const float* wp = Wc1 + (size_t)c * (HH * DD) + col * DD + f;
  unsigned r = __builtin_amdgcn_cvt_pk_fp8_f32(wp[0] * 256.f, wp[1] * 256.f, 0, false);
  r = __builtin_amdgcn_cvt_pk_fp8_f32(wp[2] * 256.f, wp[3] * 256.f, r, true);
  W[t] = r;
}

// W1s bf16 (self)
__global__ void k_wt1s(const float* __restrict__ Ws1, u16* __restrict__ W) {
  int i = blockIdx.x * 256 + threadIdx.x;       // 32768 (128 blocks)
  if (i >= 32768) return;
  int e = i & 7;
  int slot = i >> 3;
  int lane = slot & 63;
  int sk = slot >> 6;
  int kk = sk & 3, col16 = sk >> 2;
  int col = col16 * 16 + (lane & 15);
  int k = kk * 32 + (lane >> 4) * 8 + e;
  W[i] = f2bf(Ws1[col * DD + k]);
}

// W2f fragment-major bf16: conv cols scaled x64 (g2c fp8 x64), self cols x1
__global__ void k_wt2f(const float* __restrict__ Wc2, const float* __restrict__ Ws2,
                       u16* __restrict__ W) {
  int i = blockIdx.x * 256 + threadIdx.x;
  if (i >= 294912) return;
  int e = i & 7;
  int t = i >> 3;
  int rs = t & 15; t >>= 4;
  int kg = t & 3;  t >>= 2;
  int kk = t & 7;
  int col16 = t >> 3;
  int oc = col16 * 16 + rs;
  int c = oc >> 7, o = oc & 127;
  int k = kk * 32 + kg * 8 + e;
  float v = (c < CC) ? Wc2[c * (DD * HH) + o * HH + k] * 64.f
                     : Ws2[o * HH + k];
  W[i] = f2bf(v);
}

// ---------------- CSR build over seg = dst*8 + c ----------------

__global__ void k_hist(const int* __restrict__ ei, const int* __restrict__ ec,
                       int* __restrict__ counts) {
  int e = blockIdx.x * 256 + threadIdx.x;
  if (e < EE) {
    int dst = ei[EE + e];
    int c = ec[e];
    atomicAdd(&counts[dst * CC + c], 1);
  }
}

__global__ void k_offsets(const int* __restrict__ counts, int2* __restrict__ oc,
                          int* __restrict__ cursor, int* __restrict__ gcount) {
  __shared__ int lds[256];
  __shared__ int basesh;
  int tid = threadIdx.x;
  int i = blockIdx.x * 256 + tid;
  int c = (i < CC * NN) ? counts[i] : 0;
  lds[tid] = c;
  __syncthreads();
  int v = c;
  for (int s = 1; s < 256; s <<= 1) {
    int t = (tid >= s) ? lds[tid - s] : 0;
    __syncthreads();
    v += t;
    lds[tid] = v;
    __syncthreads();
  }
  if (tid == 255) basesh = atomicAdd(gcount, v);
  __syncthreads();
  int excl = basesh + v - c;
  if (i < CC * NN) {
    oc[i] = make_int2(excl, c);
    cursor[i] = excl;
  }
}

__global__ void k_fill(const int* __restrict__ ei, const int* __restrict__ ec,
                       int* __restrict__ cursor, int* __restrict__ sv) {
  int e = blockIdx.x * 256 + threadIdx.x;
  if (e < EE) {
    int src = ei[e];
    int dst = ei[EE + e];
    int c = ec[e];
    int slot = atomicAdd(&cursor[dst * CC + c], 1);
    sv[slot] = src * 8 + c;
  }
}

// ---------------- layer 1: fp8 gather (128B/edge), fp8 output ----------------

__global__ void __launch_bounds__(256) k_agg1(
    const u8* __restrict__ xf8, const int2* __restrict__ oc,
    const int* __restrict__ sv, u8* __restrict__ aggf8) {
  int item = blockIdx.x * 256 + threadIdx.x;
  if (item >= NN * 8) return;
  int dst = item >> 3, ch = item & 7;
  int eoff = ch * 16;
#pragma unroll
  for (int c = 0; c < CC; ++c) {
    int2 se = oc[dst * CC + c];
    float s[16];
#pragma unroll
    for (int q = 0; q < 16; q++) s[q] = 0.f;
    int j = 0;
    for (; j + 1 < se.y; j += 2) {
      int s0 = sv[se.x + j] >> 3;
      int s1 = sv[se.x + j + 1] >> 3;
      uint4 d0 = *(const uint4*)(xf8 + (size_t)s0 * 128 + eoff);
      uint4 d1 = *(const uint4*)(xf8 + (size_t)s1 * 128 + eoff);
      f32x2 f;
      f = __builtin_amdgcn_cvt_pk_f32_fp8(d0.x, false); s[0] += f[0]; s[1] += f[1];
      f = __builtin_amdgcn_cvt_pk_f32_fp8(d0.x, true);  s[2] += f[0]; s[3] += f[1];
      f = __builtin_amdgcn_cvt_pk_f32_fp8(d0.y, false); s[4] += f[0]; s[5] += f[1];
      f = __builtin_amdgcn_cvt_pk_f32_fp8(d0.y, true);  s[6] += f[0]; s[7] += f[1];
      f = __builtin_amdgcn_cvt_pk_f32_fp8(d0.z, false); s[8] += f[0]; s[9] += f[1];
      f = __builtin_amdgcn_cvt_pk_f32_fp8(d0.z, true);  s[10] += f[0]; s[11] += f[1];
      f = __builtin_amdgcn_cvt_pk_f32_fp8(d0.w, false); s[12] += f[0]; s[13] += f[1];
      f = __builtin_amdgcn_cvt_pk_f32_fp8(d0.w, true);  s[14] += f[0]; s[15] += f[1];
      f = __builtin_amdgcn_cvt_pk_f32_fp8(d1.x, false); s[0] += f[0]; s[1] += f[1];
      f = __builtin_amdgcn_cvt_pk_f32_fp8(d1.x, true);  s[2] += f[0]; s[3] += f[1];
      f = __builtin_amdgcn_cvt_pk_f32_fp8(d1.y, false); s[4] += f[0]; s[5] += f[1];
      f = __builtin_amdgcn_cvt_pk_f32_fp8(d1.y, true);  s[6] += f[0]; s[7] += f[1];
      f = __builtin_amdgcn_cvt_pk_f32_fp8(d1.z, false); s[8] += f[0]; s[9] += f[1];
      f = __builtin_amdgcn_cvt_pk_f32_fp8(d1.z, true);  s[10] += f[0]; s[11] += f[1];
      f = __builtin_amdgcn_cvt_pk_f32_fp8(d1.w, false); s[12] += f[0]; s[13] += f[1];
      f = __builtin_amdgcn_cvt_pk_f32_fp8(d1.w, true);  s[14] += f[0]; s[15] += f[1];
    }
    if (j < se.y) {
      int s0 = sv[se.x + j] >> 3;
      uint4 d0 = *(const uint4*)(xf8 + (size_t)s0 * 128 + eoff);
      f32x2 f;
      f = __builtin_amdgcn_cvt_pk_f32_fp8(d0.x, false); s[0] += f[0]; s[1] += f[1];
      f = __builtin_amdgcn_cvt_pk_f32_fp8(d0.x, true);  s[2] += f[0]; s[3] += f[1];
      f = __builtin_amdgcn_cvt_pk_f32_fp8(d0.y, false); s[4] += f[0]; s[5] += f[1];
      f = __builtin_amdgcn_cvt_pk_f32_fp8(d0.y, true);  s[6] += f[0]; s[7] += f[1];
      f = __builtin_amdgcn_cvt_pk_f32_fp8(d0.z, false); s[8] += f[0]; s[9] += f[1];
      f = __builtin_amdgcn_cvt_pk_f32_fp8(d0.z, true);  s[10] += f[0]; s[11] += f[1];
      f = __builtin_amdgcn_cvt_pk_f32_fp8(d0.w, false); s[12] += f[0]; s[13] += f[1];
      f = __builtin_amdgcn_cvt_pk_f32_fp8(d0.w, true);  s[14] += f[0]; s[15] += f[1];
    }
    unsigned r0 = __builtin_amdgcn_cvt_pk_fp8_f32(s[0], s[1], 0, false);
    r0 = __builtin_amdgcn_cvt_pk_fp8_f32(s[2], s[3], r0, true);
    unsigned r1 = __builtin_amdgcn_cvt_pk_fp8_f32(s[4], s[5], 0, false);
    r1 = __builtin_amdgcn_cvt_pk_fp8_f32(s[6], s[7], r1, true);
    unsigned r2 = __builtin_amdgcn_cvt_pk_fp8_f32(s[8], s[9], 0, false);
    r2 = __builtin_amdgcn_cvt_pk_fp8_f32(s[10], s[11], r2, true);
    unsigned r3 = __builtin_amdgcn_cvt_pk_fp8_f32(s[12], s[13], 0, false);
    r3 = __builtin_amdgcn_cvt_pk_fp8_f32(s[14], s[15], r3, true);
    *(uint4*)(aggf8 + ((size_t)c * NN + dst) * 128 + eoff) =
        make_uint4(r0, r1, r2, r3);
  }
}

// ---------------- layer 1 dense: 64-row blocks, fp8 phases + direct-B self --

#define LOADA8(af, p) do {                                                     \
  _Pragma("unroll") for (int kk = 0; kk < 4; ++kk)                             \
    af[kk] = *(const u64*)(aggf8 + ((size_t)(p) * NN + rowA) * 128 +           \
                           kk * 32 + kg * 8);                                  \
  } while (0)

#define LOADAS(af) do {                                                        \
  _Pragma("unroll") for (int kk = 0; kk < 4; ++kk)                             \
    af[kk] = *(const s16x8*)(xb + (size_t)rowA * DD + kk * 32 + kg * 8);       \
  } while (0)

#define STAGE8(p, buf) do {                                                    \
  _Pragma("unroll") for (int i2 = 0; i2 < 4; ++i2) {                           \
    int fc = i2 * 2 + (w >> 1);                                                \
    int kb2 = (w & 1) * 2;                                                     \
    const char* gs = (const char*)W1c8 +                                       \
        (((ch * 8 + fc) * 32 + (p) * 4 + kb2) << 9) + lane * 16;               \
    char* lp = Bs + (buf) * 16384 + ((fc * 4 + kb2) << 9);                     \
    __builtin_amdgcn_global_load_lds(                                          \
        (const __attribute__((address_space(1))) void*)gs,                     \
        (__attribute__((address_space(3))) void*)lp, 16, 0, 0);                \
  } } while (0)

#define MFMA8(af, buf) do {                                                    \
  _Pragma("unroll") for (int kk = 0; kk < 4; ++kk)                             \
  _Pragma("unroll") for (int fc = 0; fc < 8; ++fc) {                           \
    long bfr = *(const long*)(Bs + (buf) * 16384 + ((fc * 4 + kk) << 9) +      \
                              lane * 8);                                       \
    acc[fc] = __builtin_amdgcn_mfma_f32_16x16x32_fp8_fp8(                      \
        (long)af[kk], bfr, acc[fc], 0, 0, 0);                                  \
  } } while (0)

#define MFMASG(af) do {                                                        \
  _Pragma("unroll") for (int kk = 0; kk < 4; ++kk)                             \
  _Pragma("unroll") for (int fc = 0; fc < 8; ++fc) {                           \
    s16x8 bfr = *(const s16x8*)(W1s +                                          \
        ((((ch * 8 + fc) * 4 + kk) << 6) + lane) * 8);                         \
    acc[fc] = __builtin_amdgcn_mfma_f32_16x16x32_bf16(af[kk], bfr,             \
                                                      acc[fc], 0, 0, 0);       \
  } } while (0)

__global__ void __launch_bounds__(256, 5) k_gemm1s(
    const u16* __restrict__ xb, const u8* __restrict__ aggf8,
    const unsigned* __restrict__ W1c8, const u16* __restrict__ W1s,
    const float* __restrict__ b1, u16* __restrict__ hb) {
  __shared__ char Bs[32768];              // 2 x 16KB fp8 double buffer
  int ch = blockIdx.x;                    // 0..1
  int rb = blockIdx.y;                    // 0..781
  int tid = threadIdx.x;
  int w = tid >> 6, lane = tid & 63;
  int rs = lane & 15, kg = lane >> 4;
  int r0 = rb * 64 + w * 16;

  int rowA = min(r0 + rs, NN - 1);

  f32x4 acc[8];
#pragma unroll
  for (int i = 0; i < 8; i++)
#pragma unroll
    for (int q = 0; q < 4; q++) acc[i][q] = 0.f;

  u64 af8A[4], af8B[4];
  s16x8 afS[4];
  STAGE8(0, 0);
  LOADA8(af8A, 0);
  __syncthreads();

#pragma unroll
  for (int ph = 0; ph < 8; ++ph) {        // 8 fp8 colour phases
    const int cb = ph & 1, nb = cb ^ 1;
    if (ph < 7) {
      STAGE8(ph + 1, nb);
      if (cb == 0) { LOADA8(af8B, ph + 1); } else { LOADA8(af8A, ph + 1); }
    } else {
      LOADAS(afS);                        // prefetch self A
    }
    if (cb == 0) { MFMA8(af8A, 0); } else { MFMA8(af8B, 1); }
    __syncthreads();
  }
#pragma unroll
  for (int i = 0; i < 8; i++)
#pragma unroll
    for (int q = 0; q < 4; q++) acc[i][q] *= 0.00390625f;
  MFMASG(afS);

#pragma unroll
  for (int fc = 0; fc < 8; ++fc) {
    int col = ch * 128 + fc * 16 + rs;
    float bias = b1[col];
#pragma unroll
    for (int q = 0; q < 4; ++q) {
      float v = acc[fc][q] + bias;
      if (v < 0.f) v = 0.f;
      int rr = r0 + kg * 4 + q;
      if (rr < NN) hb[(size_t)rr * HH + col] = f2bf(v);
    }
  }
}

// ---------------- layer 2 multiply-first: dbuf half-panels -----------------
// Grid 782 row-blocks of 64 rows; wave = 16 rows. A stationary in registers;
// 24 panels x 24KB (3 col16 each), LDS 2x24KB double buffer; next panel
// staged during current panel's MFMA+epilogue; one barrier/panel.

#define STAGE2G(p, buf) do {                                                   \
  const char* src = (const char*)Wf + (size_t)(p) * 24576;                     \
  _Pragma("unroll") for (int i = 0; i < 6; ++i) {                              \
    const char* gs = src + ((((i * 4 + w) * 64) + lane) << 4);                 \
    char* lp = (char*)Bs + (buf) * 24576 + ((i * 4 + w) << 10);                \
    __builtin_amdgcn_global_load_lds(                                          \
        (const __attribute__((address_space(1))) void*)gs,                     \
        (__attribute__((address_space(3))) void*)lp, 16, 0, 0);                \
  } } while (0)

__global__ void __launch_bounds__(256, 3) k_gemm2g(
    const u16* __restrict__ hb, const u16* __restrict__ Wf,
    u8* __restrict__ g2c, u16* __restrict__ g2s) {
  __shared__ char Bs[49152];              // 2 x 24KB panel double buffer
  int rb = blockIdx.x;                    // 0..781
  int tid = threadIdx.x;
  int w = tid >> 6, lane = tid & 63;
  int rs = lane & 15, kg = lane >> 4;
  int r0 = rb * 64 + w * 16;

  int rowA = min(r0 + rs, NN - 1);

  s16x8 af[8];
#pragma unroll
  for (int kk = 0; kk < 8; ++kk)
    af[kk] = *(const s16x8*)(hb + (size_t)rowA * HH + kk * 32 + kg * 8);

  STAGE2G(0, 0);
  __syncthreads();

  for (int cb = 0; cb < 24; ++cb) {
    const int pb = cb & 1;
    if (cb < 23) STAGE2G(cb + 1, pb ^ 1);

    f32x4 acc[3];
#pragma unroll
    for (int i = 0; i < 3; i++)
#pragma unroll
      for (int q = 0; q < 4; q++) acc[i][q] = 0.f;

#pragma unroll
    for (int kk = 0; kk < 8; ++kk) {
#pragma unroll
      for (int fc = 0; fc < 3; ++fc) {
        s16x8 bfr = *(const s16x8*)(Bs + pb * 24576 +
                                    ((fc * 8 + kk) << 10) + lane * 16);
        acc[fc] = __builtin_amdgcn_mfma_f32_16x16x32_bf16(af[kk], bfr, acc[fc], 0, 0, 0);
      }
    }

    int c16b = cb * 3;
#pragma unroll
    for (int q = 0; q < 4; ++q) {
      int rr = r0 + kg * 4 + q;
      if (rr < NN) {
#pragma unroll
        for (int fc = 0; fc < 3; ++fc) {
          int col = (c16b + fc) * 16 + rs;
          if (col < 1024) {
            unsigned pk = __builtin_amdgcn_cvt_pk_fp8_f32(acc[fc][q],
                                                          acc[fc][q], 0, false);
            g2c[(size_t)rr * 1024 + col] = (u8)(pk & 0xFF);
          } else {
            g2s[(size_t)rr * 128 + (col - 1024)] = f2bf(acc[fc][q]);
          }
        }
      }
    }
    __syncthreads();
  }
}

// ---------------- layer 2 final: fp8 conv gather + bf16 self ----------------

__global__ void __launch_bounds__(256) k_final(
    const u8* __restrict__ g2c, const u16* __restrict__ g2s,
    const float* __restrict__ b2,
    const int2* __restrict__ oc, const int* __restrict__ sv,
    float* __restrict__ out) {
  int item = blockIdx.x * 256 + threadIdx.x;
  if (item >= NN * 8) return;
  int dst = item >> 3, ch = item & 7;
  int eoff = ch * 16;                      // 16 cols = 16 bytes (fp8)

  int st, cn;
  {
    int2 a0 = oc[dst * CC];
    int2 a7 = oc[dst * CC + 7];
    st = a0.x;
    cn = a7.x + a7.y - a0.x;
  }

  float s[16];
#pragma unroll
  for (int q = 0; q < 16; q++) s[q] = 0.f;

  for (int j = 0; j < cn; j += 4) {
    int pofs[4];
#pragma unroll
    for (int t = 0; t < 4; t++) {
      int jj = j + t;
      if (jj < cn) {
        int v = sv[st + jj];
        pofs[t] = (v >> 3) * 1024 + (v & 7) * 128;
      } else {
        pofs[t] = -1;
      }
    }
#pragma unroll
    for (int t = 0; t < 4; t++) {
      if (pofs[t] >= 0) {
        uint4 d = *(const uint4*)(g2c + (size_t)pofs[t] + eoff);
        f32x2 f;
        f = __builtin_amdgcn_cvt_pk_f32_fp8(d.x, false); s[0] += f[0]; s[1] += f[1];
        f = __builtin_amdgcn_cvt_pk_f32_fp8(d.x, true);  s[2] += f[0]; s[3] += f[1];
        f = __builtin_amdgcn_cvt_pk_f32_fp8(d.y, false); s[4] += f[0]; s[5] += f[1];
        f = __builtin_amdgcn_cvt_pk_f32_fp8(d.y, true);  s[6] += f[0]; s[7] += f[1];
        f = __builtin_amdgcn_cvt_pk_f32_fp8(d.z, false); s[8] += f[0]; s[9] += f[1];
        f = __builtin_amdgcn_cvt_pk_f32_fp8(d.z, true);  s[10] += f[0]; s[11] += f[1];
        f = __builtin_amdgcn_cvt_pk_f32_fp8(d.w, false); s[12] += f[0]; s[13] += f[1];
        f = __builtin_amdgcn_cvt_pk_f32_fp8(d.w, true);  s[14] += f[0]; s[15] += f[1];
      }
    }
  }

  s16x8 lo, hi;
  {
    const u16* sp = g2s + (size_t)dst * 128 + eoff;
    lo = *(const s16x8*)sp;
    hi = *(const s16x8*)(sp + 8);
  }
  float* op = out + (size_t)dst * DD + eoff;
#pragma unroll
  for (int q = 0; q < 8; q++) {
    float v = s[q] * 0.015625f + bf2f(lo[q]) + b2[eoff + q];
    op[q] = 1.f / (1.f + expf(10.f - v));
  }
#pragma unroll
  for (int q = 0; q < 8; q++) {
    float v = s[q + 8] * 0.015625f + bf2f(hi[q]) + b2[eoff + 8 + q];
    op[q + 8] = 1.f / (1.f + expf(10.f - v));
  }
}

// ---------------- launch ----------------

extern "C" void kernel_launch(void* const* d_in, const int* in_sizes, int n_in,
                              void* d_out, int out_size, void* d_ws, size_t ws_size,
                              hipStream_t stream) {
  const float* x   = (const float*)d_in[0];
  const int*   ei  = (const int*)d_in[1];
  const int*   ec  = (const int*)d_in[2];
  const float* Ws1 = (const float*)d_in[3];
  const float* b1  = (const float*)d_in[4];
  const float* Ws2 = (const float*)d_in[5];
  const float* b2  = (const float*)d_in[6];
  const float* Wc1 = (const float*)d_in[7];
  const float* Wc2 = (const float*)d_in[8];
  float* out = (float*)d_out;

  char* p = (char*)d_ws;
  // g2c fp8 [N,1024] (51.2MB) aliases aggf8 (51.2MB): aggf8 dead by gemm2g.
  u8*   g2c    = (u8*)p;
  u8*   aggf8  = (u8*)p;                          // [C*N,128] fp8
  u16*  g2s    = (u16*)(p + 51200000);            // [N,128] bf16 (12.8MB)
  u16*  xb     = (u16*)(p + 64000000);            // [N,128] bf16 (12.8MB)
  u16*  hb     = (u16*)(p + 76800000);            // [N,256] bf16 (25.6MB)
  unsigned* W1c8 = (unsigned*)(p + 102400000);    // 256KB fp8 frag-major
  u16*  W1s    = (u16*)(p + 102662144);           // 64KB bf16 frag-major
  u16*  W2f    = (u16*)(p + 102727680);           // 576KB bf16 frag-major
  int2* oc     = (int2*)(p + 103317504);          // [N*C] {off,cnt}
  int*  sv     = (int*)(p + 106517504);           // [E] src*8+c
  int*  counts = (int*)(p + 109717504);           // [N*C]
  int*  gcount = (int*)(p + 111317504);
  int*  cursor = (int*)(p + 111317760);           // [N*C]
  u8*   xf8    = (u8*)(p + 112917760);            // [N,128] fp8 (6.4MB)

  hipMemsetAsync(counts, 0, 1600256, stream);     // counts + gcount

  k_castx<<<3125, 256, 0, stream>>>(x, xb, xf8);
  k_wt1c8<<<256, 256, 0, stream>>>(Wc1, W1c8);
  k_wt1s<<<128, 256, 0, stream>>>(Ws1, W1s);
  k_wt2f<<<1152, 256, 0, stream>>>(Wc2, Ws2, W2f);

  k_hist<<<3125, 256, 0, stream>>>(ei, ec, counts);
  k_offsets<<<1563, 256, 0, stream>>>(counts, oc, cursor, gcount);
  k_fill<<<3125, 256, 0, stream>>>(ei, ec, cursor, sv);

  k_agg1<<<1563, 256, 0, stream>>>(xf8, oc, sv, aggf8);
  k_gemm1s<<<dim3(2, 782), 256, 0, stream>>>(xb, aggf8, W1c8, W1s, b1, hb);
  k_gemm2g<<<782, 256, 0, stream>>>(hb, W2f, g2c, g2s);
  k_final<<<1563, 256, 0, stream>>>(g2c, g2s, b2, oc, sv, out);
}

// Round 33
// 290.775 us; speedup vs baseline: 1.0139x; 1.0139x over previous
//
#include <hip/hip_runtime.h>

// GNN: 2-layer edge-coloured conv on MI355X.
// Round 33: revert gemm2g to r31 (r32 dbuf regressed); split both gathers
// 2x wider (16 threads/dst): agg1 = colour-half split (disjoint outputs),
// final = edge-half split + shfl_xor(8) combine. Halves serial load chains.

#define NN 50000
#define EE 800000
#define DD 128
#define HH 256
#define CC 8

typedef unsigned short u16;
typedef unsigned char u8;
typedef unsigned long long u64;
typedef __attribute__((ext_vector_type(8))) short s16x8;
typedef __attribute__((ext_vector_type(4))) float f32x4;
typedef __attribute__((ext_vector_type(2))) float f32x2;

__device__ __forceinline__ float bf2f(short u) {
  return __uint_as_float(((unsigned)(u16)u) << 16);
}
__device__ __forceinline__ u16 f2bf(float f) {
  unsigned u = __float_as_uint(f);
  u = (u + 0x7FFFu + ((u >> 16) & 1u)) >> 16;   // RNE
  return (u16)u;
}

// ---------------- prep ----------------

__global__ void k_castx(const float* __restrict__ x, u16* __restrict__ xb,
                        u8* __restrict__ xf8) {
  int i = blockIdx.x * 256 + threadIdx.x;       // 800000 exact (3125 blocks)
  const float4* xp = (const float4*)x + (size_t)i * 2;
  float4 a = xp[0], b = xp[1];
  s16x8 r;
  r[0] = f2bf(a.x); r[1] = f2bf(a.y); r[2] = f2bf(a.z); r[3] = f2bf(a.w);
  r[4] = f2bf(b.x); r[5] = f2bf(b.y); r[6] = f2bf(b.z); r[7] = f2bf(b.w);
  *(s16x8*)(xb + (size_t)i * 8) = r;
  unsigned p0 = __builtin_amdgcn_cvt_pk_fp8_f32(a.x, a.y, 0, false);
  p0 = __builtin_amdgcn_cvt_pk_fp8_f32(a.z, a.w, p0, true);
  unsigned p1 = __builtin_amdgcn_cvt_pk_fp8_f32(b.x, b.y, 0, false);
  p1 = __builtin_amdgcn_cvt_pk_fp8_f32(b.z, b.w, p1, true);
  *(uint2*)(xf8 + (size_t)i * 8) = make_uint2(p0, p1);
}

// W1c8 fp8, scaled x256
__global__ void k_wt1c8(const float* __restrict__ Wc1, unsigned* __restrict__ W) {
  int t = blockIdx.x * 256 + threadIdx.x;       // 65536 (256 blocks)
  if (t >= 65536) return;
  int half = t & 1;
  int slot = t >> 1;
  int lane = slot & 63;
  int sk = slot >> 6;
  int kkg = sk & 31, col16 = sk >> 5;
  int col = col16 * 16 + (lane & 15);
  int kb = kkg * 32 + (lane >> 4) * 8 + half * 4;
  int c = kb >> 7, f = kb & 127;
  const float* wp = Wc1 + (size_t)c * (HH * DD) + col * DD + f;
  unsigned r = __builtin_amdgcn_cvt_pk_fp8_f32(wp[0] * 256.f, wp[1] * 256.f, 0, false);
  r = __builtin_amdgcn_cvt_pk_fp8_f32(wp[2] * 256.f, wp[3] * 256.f, r, true);
  W[t] = r;
}

// W1s bf16 (self)
__global__ void k_wt1s(const float* __restrict__ Ws1, u16* __restrict__ W) {
  int i = blockIdx.x * 256 + threadIdx.x;       // 32768 (128 blocks)
  if (i >= 32768) return;
  int e = i & 7;
  int slot = i >> 3;
  int lane = slot & 63;
  int sk = slot >> 6;
  int kk = sk & 3, col16 = sk >> 2;
  int col = col16 * 16 + (lane & 15);
  int k = kk * 32 + (lane >> 4) * 8 + e;
  W[i] = f2bf(Ws1[col * DD + k]);
}

// W2f fragment-major bf16: conv cols scaled x64 (g2c fp8 x64), self cols x1
__global__ void k_wt2f(const float* __restrict__ Wc2, const float* __restrict__ Ws2,
                       u16* __restrict__ W) {
  int i = blockIdx.x * 256 + threadIdx.x;
  if (i >= 294912) return;
  int e = i & 7;
  int t = i >> 3;
  int rs = t & 15; t >>= 4;
  int kg = t & 3;  t >>= 2;
  int kk = t & 7;
  int col16 = t >> 3;
  int oc = col16 * 16 + rs;
  int c = oc >> 7, o = oc & 127;
  int k = kk * 32 + kg * 8 + e;
  float v = (c < CC) ? Wc2[c * (DD * HH) + o * HH + k] * 64.f
                     : Ws2[o * HH + k];
  W[i] = f2bf(v);
}

// ---------------- CSR build over seg = dst*8 + c ----------------

__global__ void k_hist(const int* __restrict__ ei, const int* __restrict__ ec,
                       int* __restrict__ counts) {
  int e = blockIdx.x * 256 + threadIdx.x;
  if (e < EE) {
    int dst = ei[EE + e];
    int c = ec[e];
    atomicAdd(&counts[dst * CC + c], 1);
  }
}

__global__ void k_offsets(const int* __restrict__ counts, int2* __restrict__ oc,
                          int* __restrict__ cursor, int* __restrict__ gcount) {
  __shared__ int lds[256];
  __shared__ int basesh;
  int tid = threadIdx.x;
  int i = blockIdx.x * 256 + tid;
  int c = (i < CC * NN) ? counts[i] : 0;
  lds[tid] = c;
  __syncthreads();
  int v = c;
  for (int s = 1; s < 256; s <<= 1) {
    int t = (tid >= s) ? lds[tid - s] : 0;
    __syncthreads();
    v += t;
    lds[tid] = v;
    __syncthreads();
  }
  if (tid == 255) basesh = atomicAdd(gcount, v);
  __syncthreads();
  int excl = basesh + v - c;
  if (i < CC * NN) {
    oc[i] = make_int2(excl, c);
    cursor[i] = excl;
  }
}

__global__ void k_fill(const int* __restrict__ ei, const int* __restrict__ ec,
                       int* __restrict__ cursor, int* __restrict__ sv) {
  int e = blockIdx.x * 256 + threadIdx.x;
  if (e < EE) {
    int src = ei[e];
    int dst = ei[EE + e];
    int c = ec[e];
    int slot = atomicAdd(&cursor[dst * CC + c], 1);
    sv[slot] = src * 8 + c;
  }
}

// ---------------- layer 1: fp8 gather, colour-half split ----------------
// thread = (dst, 16B chunk, colour-half): 800k threads, grid 3125.
// Each thread walks 4 colour segments (disjoint outputs, no reduction).

__global__ void __launch_bounds__(256) k_agg1(
    const u8* __restrict__ xf8, const int2* __restrict__ oc,
    const int* __restrict__ sv, u8* __restrict__ aggf8) {
  int item = blockIdx.x * 256 + threadIdx.x;   // NN*16 exact
  int dst = item >> 4, t = item & 15;
  int ch = t & 7, chalf = t >> 3;
  int eoff = ch * 16;
#pragma unroll
  for (int cc = 0; cc < 4; ++cc) {
    int c = chalf * 4 + cc;
    int2 se = oc[dst * CC + c];
    float s[16];
#pragma unroll
    for (int q = 0; q < 16; q++) s[q] = 0.f;
    int j = 0;
    for (; j + 1 < se.y; j += 2) {
      int s0 = sv[se.x + j] >> 3;
      int s1 = sv[se.x + j + 1] >> 3;
      uint4 d0 = *(const uint4*)(xf8 + (size_t)s0 * 128 + eoff);
      uint4 d1 = *(const uint4*)(xf8 + (size_t)s1 * 128 + eoff);
      f32x2 f;
      f = __builtin_amdgcn_cvt_pk_f32_fp8(d0.x, false); s[0] += f[0]; s[1] += f[1];
      f = __builtin_amdgcn_cvt_pk_f32_fp8(d0.x, true);  s[2] += f[0]; s[3] += f[1];
      f = __builtin_amdgcn_cvt_pk_f32_fp8(d0.y, false); s[4] += f[0]; s[5] += f[1];
      f = __builtin_amdgcn_cvt_pk_f32_fp8(d0.y, true);  s[6] += f[0]; s[7] += f[1];
      f = __builtin_amdgcn_cvt_pk_f32_fp8(d0.z, false); s[8] += f[0]; s[9] += f[1];
      f = __builtin_amdgcn_cvt_pk_f32_fp8(d0.z, true);  s[10] += f[0]; s[11] += f[1];
      f = __builtin_amdgcn_cvt_pk_f32_fp8(d0.w, false); s[12] += f[0]; s[13] += f[1];
      f = __builtin_amdgcn_cvt_pk_f32_fp8(d0.w, true);  s[14] += f[0]; s[15] += f[1];
      f = __builtin_amdgcn_cvt_pk_f32_fp8(d1.x, false); s[0] += f[0]; s[1] += f[1];
      f = __builtin_amdgcn_cvt_pk_f32_fp8(d1.x, true);  s[2] += f[0]; s[3] += f[1];
      f = __builtin_amdgcn_cvt_pk_f32_fp8(d1.y, false); s[4] += f[0]; s[5] += f[1];
      f = __builtin_amdgcn_cvt_pk_f32_fp8(d1.y, true);  s[6] += f[0]; s[7] += f[1];
      f = __builtin_amdgcn_cvt_pk_f32_fp8(d1.z, false); s[8] += f[0]; s[9] += f[1];
      f = __builtin_amdgcn_cvt_pk_f32_fp8(d1.z, true);  s[10] += f[0]; s[11] += f[1];
      f = __builtin_amdgcn_cvt_pk_f32_fp8(d1.w, false); s[12] += f[0]; s[13] += f[1];
      f = __builtin_amdgcn_cvt_pk_f32_fp8(d1.w, true);  s[14] += f[0]; s[15] += f[1];
    }
    if (j < se.y) {
      int s0 = sv[se.x + j] >> 3;
      uint4 d0 = *(const uint4*)(xf8 + (size_t)s0 * 128 + eoff);
      f32x2 f;
      f = __builtin_amdgcn_cvt_pk_f32_fp8(d0.x, false); s[0] += f[0]; s[1] += f[1];
      f = __builtin_amdgcn_cvt_pk_f32_fp8(d0.x, true);  s[2] += f[0]; s[3] += f[1];
      f = __builtin_amdgcn_cvt_pk_f32_fp8(d0.y, false); s[4] += f[0]; s[5] += f[1];
      f = __builtin_amdgcn_cvt_pk_f32_fp8(d0.y, true);  s[6] += f[0]; s[7] += f[1];
      f = __builtin_amdgcn_cvt_pk_f32_fp8(d0.z, false); s[8] += f[0]; s[9] += f[1];
      f = __builtin_amdgcn_cvt_pk_f32_fp8(d0.z, true);  s[10] += f[0]; s[11] += f[1];
      f = __builtin_amdgcn_cvt_pk_f32_fp8(d0.w, false); s[12] += f[0]; s[13] += f[1];
      f = __builtin_amdgcn_cvt_pk_f32_fp8(d0.w, true);  s[14] += f[0]; s[15] += f[1];
    }
    unsigned r0 = __builtin_amdgcn_cvt_pk_fp8_f32(s[0], s[1], 0, false);
    r0 = __builtin_amdgcn_cvt_pk_fp8_f32(s[2], s[3], r0, true);
    unsigned r1 = __builtin_amdgcn_cvt_pk_fp8_f32(s[4], s[5], 0, false);
    r1 = __builtin_amdgcn_cvt_pk_fp8_f32(s[6], s[7], r1, true);
    unsigned r2 = __builtin_amdgcn_cvt_pk_fp8_f32(s[8], s[9], 0, false);
    r2 = __builtin_amdgcn_cvt_pk_fp8_f32(s[10], s[11], r2, true);
    unsigned r3 = __builtin_amdgcn_cvt_pk_fp8_f32(s[12], s[13], 0, false);
    r3 = __builtin_amdgcn_cvt_pk_fp8_f32(s[14], s[15], r3, true);
    *(uint4*)(aggf8 + ((size_t)c * NN + dst) * 128 + eoff) =
        make_uint4(r0, r1, r2, r3);
  }
}

// ---------------- layer 1 dense: 64-row blocks, fp8 phases + direct-B self --

#define LOADA8(af, p) do {                                                     \
  _Pragma("unroll") for (int kk = 0; kk < 4; ++kk)                             \
    af[kk] = *(const u64*)(aggf8 + ((size_t)(p) * NN + rowA) * 128 +           \
                           kk * 32 + kg * 8);                                  \
  } while (0)

#define LOADAS(af) do {                                                        \
  _Pragma("unroll") for (int kk = 0; kk < 4; ++kk)                             \
    af[kk] = *(const s16x8*)(xb + (size_t)rowA * DD + kk * 32 + kg * 8);       \
  } while (0)

#define STAGE8(p, buf) do {                                                    \
  _Pragma("unroll") for (int i2 = 0; i2 < 4; ++i2) {                           \
    int fc = i2 * 2 + (w >> 1);                                                \
    int kb2 = (w & 1) * 2;                                                     \
    const char* gs = (const char*)W1c8 +                                       \
        (((ch * 8 + fc) * 32 + (p) * 4 + kb2) << 9) + lane * 16;               \
    char* lp = Bs + (buf) * 16384 + ((fc * 4 + kb2) << 9);                     \
    __builtin_amdgcn_global_load_lds(                                          \
        (const __attribute__((address_space(1))) void*)gs,                     \
        (__attribute__((address_space(3))) void*)lp, 16, 0, 0);                \
  } } while (0)

#define MFMA8(af, buf) do {                                                    \
  _Pragma("unroll") for (int kk = 0; kk < 4; ++kk)                             \
  _Pragma("unroll") for (int fc = 0; fc < 8; ++fc) {                           \
    long bfr = *(const long*)(Bs + (buf) * 16384 + ((fc * 4 + kk) << 9) +      \
                              lane * 8);                                       \
    acc[fc] = __builtin_amdgcn_mfma_f32_16x16x32_fp8_fp8(                      \
        (long)af[kk], bfr, acc[fc], 0, 0, 0);                                  \
  } } while (0)

#define MFMASG(af) do {                                                        \
  _Pragma("unroll") for (int kk = 0; kk < 4; ++kk)                             \
  _Pragma("unroll") for (int fc = 0; fc < 8; ++fc) {                           \
    s16x8 bfr = *(const s16x8*)(W1s +                                          \
        ((((ch * 8 + fc) * 4 + kk) << 6) + lane) * 8);                         \
    acc[fc] = __builtin_amdgcn_mfma_f32_16x16x32_bf16(af[kk], bfr,             \
                                                      acc[fc], 0, 0, 0);       \
  } } while (0)

__global__ void __launch_bounds__(256, 5) k_gemm1s(
    const u16* __restrict__ xb, const u8* __restrict__ aggf8,
    const unsigned* __restrict__ W1c8, const u16* __restrict__ W1s,
    const float* __restrict__ b1, u16* __restrict__ hb) {
  __shared__ char Bs[32768];              // 2 x 16KB fp8 double buffer
  int ch = blockIdx.x;                    // 0..1
  int rb = blockIdx.y;                    // 0..781
  int tid = threadIdx.x;
  int w = tid >> 6, lane = tid & 63;
  int rs = lane & 15, kg = lane >> 4;
  int r0 = rb * 64 + w * 16;

  int rowA = min(r0 + rs, NN - 1);

  f32x4 acc[8];
#pragma unroll
  for (int i = 0; i < 8; i++)
#pragma unroll
    for (int q = 0; q < 4; q++) acc[i][q] = 0.f;

  u64 af8A[4], af8B[4];
  s16x8 afS[4];
  STAGE8(0, 0);
  LOADA8(af8A, 0);
  __syncthreads();

#pragma unroll
  for (int ph = 0; ph < 8; ++ph) {        // 8 fp8 colour phases
    const int cb = ph & 1, nb = cb ^ 1;
    if (ph < 7) {
      STAGE8(ph + 1, nb);
      if (cb == 0) { LOADA8(af8B, ph + 1); } else { LOADA8(af8A, ph + 1); }
    } else {
      LOADAS(afS);                        // prefetch self A
    }
    if (cb == 0) { MFMA8(af8A, 0); } else { MFMA8(af8B, 1); }
    __syncthreads();
  }
#pragma unroll
  for (int i = 0; i < 8; i++)
#pragma unroll
    for (int q = 0; q < 4; q++) acc[i][q] *= 0.00390625f;
  MFMASG(afS);

#pragma unroll
  for (int fc = 0; fc < 8; ++fc) {
    int col = ch * 128 + fc * 16 + rs;
    float bias = b1[col];
#pragma unroll
    for (int q = 0; q < 4; ++q) {
      float v = acc[fc][q] + bias;
      if (v < 0.f) v = 0.f;
      int rr = r0 + kg * 4 + q;
      if (rr < NN) hb[(size_t)rr * HH + col] = f2bf(v);
    }
  }
}

// ---------------- layer 2 multiply-first: A-stationary, 64-row blocks -------
// (round-31 version: single 48KB panel, 12 iterations)

__global__ void __launch_bounds__(256, 3) k_gemm2g(
    const u16* __restrict__ hb, const u16* __restrict__ Wf,
    u8* __restrict__ g2c, u16* __restrict__ g2s) {
  __shared__ u16 Bs[24576];               // 48KB panel
  int rb = blockIdx.x;                    // 0..781
  int tid = threadIdx.x;
  int w = tid >> 6, lane = tid & 63;
  int rs = lane & 15, kg = lane >> 4;
  int r0 = rb * 64 + w * 16;

  int rowA = min(r0 + rs, NN - 1);

  s16x8 af[8];
#pragma unroll
  for (int kk = 0; kk < 8; ++kk)
    af[kk] = *(const s16x8*)(hb + (size_t)rowA * HH + kk * 32 + kg * 8);

  for (int cb = 0; cb < 12; ++cb) {
    {
      const char* src = (const char*)(Wf + (size_t)cb * 24576);
#pragma unroll
      for (int i = 0; i < 12; ++i) {
        const char* gs = src + ((i * 256 + w * 64 + lane) << 4);
        char* lp = (char*)Bs + ((i * 256 + w * 64) << 4);
        __builtin_amdgcn_global_load_lds(
            (const __attribute__((address_space(1))) void*)gs,
            (__attribute__((address_space(3))) void*)lp, 16, 0, 0);
      }
    }
    __syncthreads();

    int c16b = cb * 6;
    f32x4 acc[6];
#pragma unroll
    for (int i = 0; i < 6; i++)
#pragma unroll
      for (int q = 0; q < 4; q++) acc[i][q] = 0.f;

#pragma unroll
    for (int kk = 0; kk < 8; ++kk) {
#pragma unroll
      for (int fc = 0; fc < 6; ++fc) {
        s16x8 bfr = *(const s16x8*)(Bs + ((fc * 8 + kk) * 64 + lane) * 8);
        acc[fc] = __builtin_amdgcn_mfma_f32_16x16x32_bf16(af[kk], bfr, acc[fc], 0, 0, 0);
      }
    }

#pragma unroll
    for (int q = 0; q < 4; ++q) {
      int rr = r0 + kg * 4 + q;
      if (rr < NN) {
#pragma unroll
        for (int fc = 0; fc < 6; ++fc) {
          int col = (c16b + fc) * 16 + rs;
          if (col < 1024) {
            unsigned pk = __builtin_amdgcn_cvt_pk_fp8_f32(acc[fc][q],
                                                          acc[fc][q], 0, false);
            g2c[(size_t)rr * 1024 + col] = (u8)(pk & 0xFF);
          } else {
            g2s[(size_t)rr * 128 + (col - 1024)] = f2bf(acc[fc][q]);
          }
        }
      }
    }
    __syncthreads();
  }
}

// ---------------- layer 2 final: edge-half split gather + shfl combine ------
// thread = (dst, 16B chunk, edge-half): 800k threads, grid 3125. Halves
// interleave 4-edge batches; shfl_xor(8) combines; half 0 writes.

__global__ void __launch_bounds__(256) k_final(
    const u8* __restrict__ g2c, const u16* __restrict__ g2s,
    const float* __restrict__ b2,
    const int2* __restrict__ oc, const int* __restrict__ sv,
    float* __restrict__ out) {
  int item = blockIdx.x * 256 + threadIdx.x;   // NN*16 exact
  int dst = item >> 4, t = item & 15;
  int ch = t & 7, half = t >> 3;
  int eoff = ch * 16;

  int st, cn;
  {
    int2 a0 = oc[dst * CC];
    int2 a7 = oc[dst * CC + 7];
    st = a0.x;
    cn = a7.x + a7.y - a0.x;
  }

  float s[16];
#pragma unroll
  for (int q = 0; q < 16; q++) s[q] = 0.f;

  for (int j = half * 4; j < cn; j += 8) {
    int pofs[4];
#pragma unroll
    for (int t2 = 0; t2 < 4; t2++) {
      int jj = j + t2;
      if (jj < cn) {
        int v = sv[st + jj];
        pofs[t2] = (v >> 3) * 1024 + (v & 7) * 128;
      } else {
        pofs[t2] = -1;
      }
    }
#pragma unroll
    for (int t2 = 0; t2 < 4; t2++) {
      if (pofs[t2] >= 0) {
        uint4 d = *(const uint4*)(g2c + (size_t)pofs[t2] + eoff);
        f32x2 f;
        f = __builtin_amdgcn_cvt_pk_f32_fp8(d.x, false); s[0] += f[0]; s[1] += f[1];
        f = __builtin_amdgcn_cvt_pk_f32_fp8(d.x, true);  s[2] += f[0]; s[3] += f[1];
        f = __builtin_amdgcn_cvt_pk_f32_fp8(d.y, false); s[4] += f[0]; s[5] += f[1];
        f = __builtin_amdgcn_cvt_pk_f32_fp8(d.y, true);  s[6] += f[0]; s[7] += f[1];
        f = __builtin_amdgcn_cvt_pk_f32_fp8(d.z, false); s[8] += f[0]; s[9] += f[1];
        f = __builtin_amdgcn_cvt_pk_f32_fp8(d.z, true);  s[10] += f[0]; s[11] += f[1];
        f = __builtin_amdgcn_cvt_pk_f32_fp8(d.w, false); s[12] += f[0]; s[13] += f[1];
        f = __builtin_amdgcn_cvt_pk_f32_fp8(d.w, true);  s[14] += f[0]; s[15] += f[1];
      }
    }
  }

  // combine halves (partner lane differs by 8, always in-wave: 16-thread
  // dst-groups are 16-aligned in lane space)
#pragma unroll
  for (int q = 0; q < 16; q++) s[q] += __shfl_xor(s[q], 8);

  if (half == 0) {
    s16x8 lo, hi;
    {
      const u16* sp = g2s + (size_t)dst * 128 + eoff;
      lo = *(const s16x8*)sp;
      hi = *(const s16x8*)(sp + 8);
    }
    float* op = out + (size_t)dst * DD + eoff;
#pragma unroll
    for (int q = 0; q < 8; q++) {
      float v = s[q] * 0.015625f + bf2f(lo[q]) + b2[eoff + q];
      op[q] = 1.f / (1.f + expf(10.f - v));
    }
#pragma unroll
    for (int q = 0; q < 8; q++) {
      float v = s[q + 8] * 0.015625f + bf2f(hi[q]) + b2[eoff + 8 + q];
      op[q + 8] = 1.f / (1.f + expf(10.f - v));
    }
  }
}

// ---------------- launch ----------------

extern "C" void kernel_launch(void* const* d_in, const int* in_sizes, int n_in,
                              void* d_out, int out_size, void* d_ws, size_t ws_size,
                              hipStream_t stream) {
  const float* x   = (const float*)d_in[0];
  const int*   ei  = (const int*)d_in[1];
  const int*   ec  = (const int*)d_in[2];
  const float* Ws1 = (const float*)d_in[3];
  const float* b1  = (const float*)d_in[4];
  const float* Ws2 = (const float*)d_in[5];
  const float* b2  = (const float*)d_in[6];
  const float* Wc1 = (const float*)d_in[7];
  const float* Wc2 = (const float*)d_in[8];
  float* out = (float*)d_out;

  char* p = (char*)d_ws;
  // g2c fp8 [N,1024] (51.2MB) aliases aggf8 (51.2MB): aggf8 dead by gemm2g.
  u8*   g2c    = (u8*)p;
  u8*   aggf8  = (u8*)p;                          // [C*N,128] fp8
  u16*  g2s    = (u16*)(p + 51200000);            // [N,128] bf16 (12.8MB)
  u16*  xb     = (u16*)(p + 64000000);            // [N,128] bf16 (12.8MB)
  u16*  hb     = (u16*)(p + 76800000);            // [N,256] bf16 (25.6MB)
  unsigned* W1c8 = (unsigned*)(p + 102400000);    // 256KB fp8 frag-major
  u16*  W1s    = (u16*)(p + 102662144);           // 64KB bf16 frag-major
  u16*  W2f    = (u16*)(p + 102727680);           // 576KB bf16 frag-major
  int2* oc     = (int2*)(p + 103317504);          // [N*C] {off,cnt}
  int*  sv     = (int*)(p + 106517504);           // [E] src*8+c
  int*  counts = (int*)(p + 109717504);           // [N*C]
  int*  gcount = (int*)(p + 111317504);
  int*  cursor = (int*)(p + 111317760);           // [N*C]
  u8*   xf8    = (u8*)(p + 112917760);            // [N,128] fp8 (6.4MB)

  hipMemsetAsync(counts, 0, 1600256, stream);     // counts + gcount

  k_castx<<<3125, 256, 0, stream>>>(x, xb, xf8);
  k_wt1c8<<<256, 256, 0, stream>>>(Wc1, W1c8);
  k_wt1s<<<128, 256, 0, stream>>>(Ws1, W1s);
  k_wt2f<<<1152, 256, 0, stream>>>(Wc2, Ws2, W2f);

  k_hist<<<3125, 256, 0, stream>>>(ei, ec, counts);
  k_offsets<<<1563, 256, 0, stream>>>(counts, oc, cursor, gcount);
  k_fill<<<3125, 256, 0, stream>>>(ei, ec, cursor, sv);

  k_agg1<<<3125, 256, 0, stream>>>(xf8, oc, sv, aggf8);
  k_gemm1s<<<dim3(2, 782), 256, 0, stream>>>(xb, aggf8, W1c8, W1s, b1, hb);
  k_gemm2g<<<782, 256, 0, stream>>>(hb, W2f, g2c, g2s);
  k_final<<<3125, 256, 0, stream>>>(g2c, g2s, b2, oc, sv, out);
}

// Round 34
// 284.536 us; speedup vs baseline: 1.0361x; 1.0219x over previous
//
#include <hip/hip_runtime.h>

// GNN: 2-layer edge-coloured conv on MI355X.
// Round 34: fuse the 5 independent prep kernels (castx/wt1c8/wt1s/wt2f/hist)
// into one k_prep (block-range dispatch) — removes 4 dispatch drain/ramp
// boundaries. All numerics = round 33 (passed, 290.8us).

#define NN 50000
#define EE 800000
#define DD 128
#define HH 256
#define CC 8

typedef unsigned short u16;
typedef unsigned char u8;
typedef unsigned long long u64;
typedef __attribute__((ext_vector_type(8))) short s16x8;
typedef __attribute__((ext_vector_type(4))) float f32x4;
typedef __attribute__((ext_vector_type(2))) float f32x2;

__device__ __forceinline__ float bf2f(short u) {
  return __uint_as_float(((unsigned)(u16)u) << 16);
}
__device__ __forceinline__ u16 f2bf(float f) {
  unsigned u = __float_as_uint(f);
  u = (u + 0x7FFFu + ((u >> 16) & 1u)) >> 16;   // RNE
  return (u16)u;
}

// ---------------- fused prep: castx | wt1c8 | wt1s | wt2f | hist ----------

__global__ void __launch_bounds__(256) k_prep(
    const float* __restrict__ x, u16* __restrict__ xb, u8* __restrict__ xf8,
    const float* __restrict__ Wc1, unsigned* __restrict__ W1c8,
    const float* __restrict__ Ws1, u16* __restrict__ W1s,
    const float* __restrict__ Wc2, const float* __restrict__ Ws2,
    u16* __restrict__ W2f,
    const int* __restrict__ ei, const int* __restrict__ ec,
    int* __restrict__ counts) {
  int b = blockIdx.x;
  int tid = threadIdx.x;
  if (b < 3125) {
    // castx: i in [0, 800000)
    int i = b * 256 + tid;
    const float4* xp = (const float4*)x + (size_t)i * 2;
    float4 a = xp[0], bb = xp[1];
    s16x8 r;
    r[0] = f2bf(a.x); r[1] = f2bf(a.y); r[2] = f2bf(a.z); r[3] = f2bf(a.w);
    r[4] = f2bf(bb.x); r[5] = f2bf(bb.y); r[6] = f2bf(bb.z); r[7] = f2bf(bb.w);
    *(s16x8*)(xb + (size_t)i * 8) = r;
    unsigned p0 = __builtin_amdgcn_cvt_pk_fp8_f32(a.x, a.y, 0, false);
    p0 = __builtin_amdgcn_cvt_pk_fp8_f32(a.z, a.w, p0, true);
    unsigned p1 = __builtin_amdgcn_cvt_pk_fp8_f32(bb.x, bb.y, 0, false);
    p1 = __builtin_amdgcn_cvt_pk_fp8_f32(bb.z, bb.w, p1, true);
    *(uint2*)(xf8 + (size_t)i * 8) = make_uint2(p0, p1);
  } else if (b < 3381) {
    // wt1c8: t in [0, 65536)
    int t = (b - 3125) * 256 + tid;
    int half = t & 1;
    int slot = t >> 1;
    int lane = slot & 63;
    int sk = slot >> 6;
    int kkg = sk & 31, col16 = sk >> 5;
    int col = col16 * 16 + (lane & 15);
    int kb = kkg * 32 + (lane >> 4) * 8 + half * 4;
    int c = kb >> 7, f = kb & 127;
    const float* wp = Wc1 + (size_t)c * (HH * DD) + col * DD + f;
    unsigned r = __builtin_amdgcn_cvt_pk_fp8_f32(wp[0] * 256.f, wp[1] * 256.f, 0, false);
    r = __builtin_amdgcn_cvt_pk_fp8_f32(wp[2] * 256.f, wp[3] * 256.f, r, true);
    W1c8[t] = r;
  } else if (b < 3509) {
    // wt1s: i in [0, 32768)
    int i = (b - 3381) * 256 + tid;
    int e = i & 7;
    int slot = i >> 3;
    int lane = slot & 63;
    int sk = slot >> 6;
    int kk = sk & 3, col16 = sk >> 2;
    int col = col16 * 16 + (lane & 15);
    int k = kk * 32 + (lane >> 4) * 8 + e;
    W1s[i] = f2bf(Ws1[col * DD + k]);
  } else if (b < 4661) {
    // wt2f: i in [0, 294912)
    int i = (b - 3509) * 256 + tid;
    if (i < 294912) {
      int e = i & 7;
      int t = i >> 3;
      int rs = t & 15; t >>= 4;
      int kg = t & 3;  t >>= 2;
      int kk = t & 7;
      int col16 = t >> 3;
      int oc2 = col16 * 16 + rs;
      int c = oc2 >> 7, o = oc2 & 127;
      int k = kk * 32 + kg * 8 + e;
      float v = (c < CC) ? Wc2[c * (DD * HH) + o * HH + k] * 64.f
                         : Ws2[o * HH + k];
      W2f[i] = f2bf(v);
    }
  } else {
    // hist: e in [0, 800000)
    int e = (b - 4661) * 256 + tid;
    if (e < EE) {
      int dst = ei[EE + e];
      int c = ec[e];
      atomicAdd(&counts[dst * CC + c], 1);
    }
  }
}

// ---------------- CSR build over seg = dst*8 + c ----------------

__global__ void k_offsets(const int* __restrict__ counts, int2* __restrict__ oc,
                          int* __restrict__ cursor, int* __restrict__ gcount) {
  __shared__ int lds[256];
  __shared__ int basesh;
  int tid = threadIdx.x;
  int i = blockIdx.x * 256 + tid;
  int c = (i < CC * NN) ? counts[i] : 0;
  lds[tid] = c;
  __syncthreads();
  int v = c;
  for (int s = 1; s < 256; s <<= 1) {
    int t = (tid >= s) ? lds[tid - s] : 0;
    __syncthreads();
    v += t;
    lds[tid] = v;
    __syncthreads();
  }
  if (tid == 255) basesh = atomicAdd(gcount, v);
  __syncthreads();
  int excl = basesh + v - c;
  if (i < CC * NN) {
    oc[i] = make_int2(excl, c);
    cursor[i] = excl;
  }
}

__global__ void k_fill(const int* __restrict__ ei, const int* __restrict__ ec,
                       int* __restrict__ cursor, int* __restrict__ sv) {
  int e = blockIdx.x * 256 + threadIdx.x;
  if (e < EE) {
    int src = ei[e];
    int dst = ei[EE + e];
    int c = ec[e];
    int slot = atomicAdd(&cursor[dst * CC + c], 1);
    sv[slot] = src * 8 + c;
  }
}

// ---------------- layer 1: fp8 gather, colour-half split ----------------

__global__ void __launch_bounds__(256) k_agg1(
    const u8* __restrict__ xf8, const int2* __restrict__ oc,
    const int* __restrict__ sv, u8* __restrict__ aggf8) {
  int item = blockIdx.x * 256 + threadIdx.x;   // NN*16 exact
  int dst = item >> 4, t = item & 15;
  int ch = t & 7, chalf = t >> 3;
  int eoff = ch * 16;
#pragma unroll
  for (int cc = 0; cc < 4; ++cc) {
    int c = chalf * 4 + cc;
    int2 se = oc[dst * CC + c];
    float s[16];
#pragma unroll
    for (int q = 0; q < 16; q++) s[q] = 0.f;
    int j = 0;
    for (; j + 1 < se.y; j += 2) {
      int s0 = sv[se.x + j] >> 3;
      int s1 = sv[se.x + j + 1] >> 3;
      uint4 d0 = *(const uint4*)(xf8 + (size_t)s0 * 128 + eoff);
      uint4 d1 = *(const uint4*)(xf8 + (size_t)s1 * 128 + eoff);
      f32x2 f;
      f = __builtin_amdgcn_cvt_pk_f32_fp8(d0.x, false); s[0] += f[0]; s[1] += f[1];
      f = __builtin_amdgcn_cvt_pk_f32_fp8(d0.x, true);  s[2] += f[0]; s[3] += f[1];
      f = __builtin_amdgcn_cvt_pk_f32_fp8(d0.y, false); s[4] += f[0]; s[5] += f[1];
      f = __builtin_amdgcn_cvt_pk_f32_fp8(d0.y, true);  s[6] += f[0]; s[7] += f[1];
      f = __builtin_amdgcn_cvt_pk_f32_fp8(d0.z, false); s[8] += f[0]; s[9] += f[1];
      f = __builtin_amdgcn_cvt_pk_f32_fp8(d0.z, true);  s[10] += f[0]; s[11] += f[1];
      f = __builtin_amdgcn_cvt_pk_f32_fp8(d0.w, false); s[12] += f[0]; s[13] += f[1];
      f = __builtin_amdgcn_cvt_pk_f32_fp8(d0.w, true);  s[14] += f[0]; s[15] += f[1];
      f = __builtin_amdgcn_cvt_pk_f32_fp8(d1.x, false); s[0] += f[0]; s[1] += f[1];
      f = __builtin_amdgcn_cvt_pk_f32_fp8(d1.x, true);  s[2] += f[0]; s[3] += f[1];
      f = __builtin_amdgcn_cvt_pk_f32_fp8(d1.y, false); s[4] += f[0]; s[5] += f[1];
      f = __builtin_amdgcn_cvt_pk_f32_fp8(d1.y, true);  s[6] += f[0]; s[7] += f[1];
      f = __builtin_amdgcn_cvt_pk_f32_fp8(d1.z, false); s[8] += f[0]; s[9] += f[1];
      f = __builtin_amdgcn_cvt_pk_f32_fp8(d1.z, true);  s[10] += f[0]; s[11] += f[1];
      f = __builtin_amdgcn_cvt_pk_f32_fp8(d1.w, false); s[12] += f[0]; s[13] += f[1];
      f = __builtin_amdgcn_cvt_pk_f32_fp8(d1.w, true);  s[14] += f[0]; s[15] += f[1];
    }
    if (j < se.y) {
      int s0 = sv[se.x + j] >> 3;
      uint4 d0 = *(const uint4*)(xf8 + (size_t)s0 * 128 + eoff);
      f32x2 f;
      f = __builtin_amdgcn_cvt_pk_f32_fp8(d0.x, false); s[0] += f[0]; s[1] += f[1];
      f = __builtin_amdgcn_cvt_pk_f32_fp8(d0.x, true);  s[2] += f[0]; s[3] += f[1];
      f = __builtin_amdgcn_cvt_pk_f32_fp8(d0.y, false); s[4] += f[0]; s[5] += f[1];
      f = __builtin_amdgcn_cvt_pk_f32_fp8(d0.y, true);  s[6] += f[0]; s[7] += f[1];
      f = __builtin_amdgcn_cvt_pk_f32_fp8(d0.z, false); s[8] += f[0]; s[9] += f[1];
      f = __builtin_amdgcn_cvt_pk_f32_fp8(d0.z, true);  s[10] += f[0]; s[11] += f[1];
      f = __builtin_amdgcn_cvt_pk_f32_fp8(d0.w, false); s[12] += f[0]; s[13] += f[1];
      f = __builtin_amdgcn_cvt_pk_f32_fp8(d0.w, true);  s[14] += f[0]; s[15] += f[1];
    }
    unsigned r0 = __builtin_amdgcn_cvt_pk_fp8_f32(s[0], s[1], 0, false);
    r0 = __builtin_amdgcn_cvt_pk_fp8_f32(s[2], s[3], r0, true);
    unsigned r1 = __builtin_amdgcn_cvt_pk_fp8_f32(s[4], s[5], 0, false);
    r1 = __builtin_amdgcn_cvt_pk_fp8_f32(s[6], s[7], r1, true);
    unsigned r2 = __builtin_amdgcn_cvt_pk_fp8_f32(s[8], s[9], 0, false);
    r2 = __builtin_amdgcn_cvt_pk_fp8_f32(s[10], s[11], r2, true);
    unsigned r3 = __builtin_amdgcn_cvt_pk_fp8_f32(s[12], s[13], 0, false);
    r3 = __builtin_amdgcn_cvt_pk_fp8_f32(s[14], s[15], r3, true);
    *(uint4*)(aggf8 + ((size_t)c * NN + dst) * 128 + eoff) =
        make_uint4(r0, r1, r2, r3);
  }
}

// ---------------- layer 1 dense: 64-row blocks, fp8 phases + direct-B self --

#define LOADA8(af, p) do {                                                     \
  _Pragma("unroll") for (int kk = 0; kk < 4; ++kk)                             \
    af[kk] = *(const u64*)(aggf8 + ((size_t)(p) * NN + rowA) * 128 +           \
                           kk * 32 + kg * 8);                                  \
  } while (0)

#define LOADAS(af) do {                                                        \
  _Pragma("unroll") for (int kk = 0; kk < 4; ++kk)                             \
    af[kk] = *(const s16x8*)(xb + (size_t)rowA * DD + kk * 32 + kg * 8);       \
  } while (0)

#define STAGE8(p, buf) do {                                                    \
  _Pragma("unroll") for (int i2 = 0; i2 < 4; ++i2) {                           \
    int fc = i2 * 2 + (w >> 1);                                                \
    int kb2 = (w & 1) * 2;                                                     \
    const char* gs = (const char*)W1c8 +                                       \
        (((ch * 8 + fc) * 32 + (p) * 4 + kb2) << 9) + lane * 16;               \
    char* lp = Bs + (buf) * 16384 + ((fc * 4 + kb2) << 9);                     \
    __builtin_amdgcn_global_load_lds(                                          \
        (const __attribute__((address_space(1))) void*)gs,                     \
        (__attribute__((address_space(3))) void*)lp, 16, 0, 0);                \
  } } while (0)

#define MFMA8(af, buf) do {                                                    \
  _Pragma("unroll") for (int kk = 0; kk < 4; ++kk)                             \
  _Pragma("unroll") for (int fc = 0; fc < 8; ++fc) {                           \
    long bfr = *(const long*)(Bs + (buf) * 16384 + ((fc * 4 + kk) << 9) +      \
                              lane * 8);                                       \
    acc[fc] = __builtin_amdgcn_mfma_f32_16x16x32_fp8_fp8(                      \
        (long)af[kk], bfr, acc[fc], 0, 0, 0);                                  \
  } } while (0)

#define MFMASG(af) do {                                                        \
  _Pragma("unroll") for (int kk = 0; kk < 4; ++kk)                             \
  _Pragma("unroll") for (int fc = 0; fc < 8; ++fc) {                           \
    s16x8 bfr = *(const s16x8*)(W1s +                                          \
        ((((ch * 8 + fc) * 4 + kk) << 6) + lane) * 8);                         \
    acc[fc] = __builtin_amdgcn_mfma_f32_16x16x32_bf16(af[kk], bfr,             \
                                                      acc[fc], 0, 0, 0);       \
  } } while (0)

__global__ void __launch_bounds__(256, 5) k_gemm1s(
    const u16* __restrict__ xb, const u8* __restrict__ aggf8,
    const unsigned* __restrict__ W1c8, const u16* __restrict__ W1s,
    const float* __restrict__ b1, u16* __restrict__ hb) {
  __shared__ char Bs[32768];              // 2 x 16KB fp8 double buffer
  int ch = blockIdx.x;                    // 0..1
  int rb = blockIdx.y;                    // 0..781
  int tid = threadIdx.x;
  int w = tid >> 6, lane = tid & 63;
  int rs = lane & 15, kg = lane >> 4;
  int r0 = rb * 64 + w * 16;

  int rowA = min(r0 + rs, NN - 1);

  f32x4 acc[8];
#pragma unroll
  for (int i = 0; i < 8; i++)
#pragma unroll
    for (int q = 0; q < 4; q++) acc[i][q] = 0.f;

  u64 af8A[4], af8B[4];
  s16x8 afS[4];
  STAGE8(0, 0);
  LOADA8(af8A, 0);
  __syncthreads();

#pragma unroll
  for (int ph = 0; ph < 8; ++ph) {        // 8 fp8 colour phases
    const int cb = ph & 1, nb = cb ^ 1;
    if (ph < 7) {
      STAGE8(ph + 1, nb);
      if (cb == 0) { LOADA8(af8B, ph + 1); } else { LOADA8(af8A, ph + 1); }
    } else {
      LOADAS(afS);                        // prefetch self A
    }
    if (cb == 0) { MFMA8(af8A, 0); } else { MFMA8(af8B, 1); }
    __syncthreads();
  }
#pragma unroll
  for (int i = 0; i < 8; i++)
#pragma unroll
    for (int q = 0; q < 4; q++) acc[i][q] *= 0.00390625f;
  MFMASG(afS);

#pragma unroll
  for (int fc = 0; fc < 8; ++fc) {
    int col = ch * 128 + fc * 16 + rs;
    float bias = b1[col];
#pragma unroll
    for (int q = 0; q < 4; ++q) {
      float v = acc[fc][q] + bias;
      if (v < 0.f) v = 0.f;
      int rr = r0 + kg * 4 + q;
      if (rr < NN) hb[(size_t)rr * HH + col] = f2bf(v);
    }
  }
}

// ---------------- layer 2 multiply-first: A-stationary, 64-row blocks -------

__global__ void __launch_bounds__(256, 3) k_gemm2g(
    const u16* __restrict__ hb, const u16* __restrict__ Wf,
    u8* __restrict__ g2c, u16* __restrict__ g2s) {
  __shared__ u16 Bs[24576];               // 48KB panel
  int rb = blockIdx.x;                    // 0..781
  int tid = threadIdx.x;
  int w = tid >> 6, lane = tid & 63;
  int rs = lane & 15, kg = lane >> 4;
  int r0 = rb * 64 + w * 16;

  int rowA = min(r0 + rs, NN - 1);

  s16x8 af[8];
#pragma unroll
  for (int kk = 0; kk < 8; ++kk)
    af[kk] = *(const s16x8*)(hb + (size_t)rowA * HH + kk * 32 + kg * 8);

  for (int cb = 0; cb < 12; ++cb) {
    {
      const char* src = (const char*)(Wf + (size_t)cb * 24576);
#pragma unroll
      for (int i = 0; i < 12; ++i) {
        const char* gs = src + ((i * 256 + w * 64 + lane) << 4);
        char* lp = (char*)Bs + ((i * 256 + w * 64) << 4);
        __builtin_amdgcn_global_load_lds(
            (const __attribute__((address_space(1))) void*)gs,
            (__attribute__((address_space(3))) void*)lp, 16, 0, 0);
      }
    }
    __syncthreads();

    int c16b = cb * 6;
    f32x4 acc[6];
#pragma unroll
    for (int i = 0; i < 6; i++)
#pragma unroll
      for (int q = 0; q < 4; q++) acc[i][q] = 0.f;

#pragma unroll
    for (int kk = 0; kk < 8; ++kk) {
#pragma unroll
      for (int fc = 0; fc < 6; ++fc) {
        s16x8 bfr = *(const s16x8*)(Bs + ((fc * 8 + kk) * 64 + lane) * 8);
        acc[fc] = __builtin_amdgcn_mfma_f32_16x16x32_bf16(af[kk], bfr, acc[fc], 0, 0, 0);
      }
    }

#pragma unroll
    for (int q = 0; q < 4; ++q) {
      int rr = r0 + kg * 4 + q;
      if (rr < NN) {
#pragma unroll
        for (int fc = 0; fc < 6; ++fc) {
          int col = (c16b + fc) * 16 + rs;
          if (col < 1024) {
            unsigned pk = __builtin_amdgcn_cvt_pk_fp8_f32(acc[fc][q],
                                                          acc[fc][q], 0, false);
            g2c[(size_t)rr * 1024 + col] = (u8)(pk & 0xFF);
          } else {
            g2s[(size_t)rr * 128 + (col - 1024)] = f2bf(acc[fc][q]);
          }
        }
      }
    }
    __syncthreads();
  }
}

// ---------------- layer 2 final: edge-half split gather + shfl combine ------

__global__ void __launch_bounds__(256) k_final(
    const u8* __restrict__ g2c, const u16* __restrict__ g2s,
    const float* __restrict__ b2,
    const int2* __restrict__ oc, const int* __restrict__ sv,
    float* __restrict__ out) {
  int item = blockIdx.x * 256 + threadIdx.x;   // NN*16 exact
  int dst = item >> 4, t = item & 15;
  int ch = t & 7, half = t >> 3;
  int eoff = ch * 16;

  int st, cn;
  {
    int2 a0 = oc[dst * CC];
    int2 a7 = oc[dst * CC + 7];
    st = a0.x;
    cn = a7.x + a7.y - a0.x;
  }

  float s[16];
#pragma unroll
  for (int q = 0; q < 16; q++) s[q] = 0.f;

  for (int j = half * 4; j < cn; j += 8) {
    int pofs[4];
#pragma unroll
    for (int t2 = 0; t2 < 4; t2++) {
      int jj = j + t2;
      if (jj < cn) {
        int v = sv[st + jj];
        pofs[t2] = (v >> 3) * 1024 + (v & 7) * 128;
      } else {
        pofs[t2] = -1;
      }
    }
#pragma unroll
    for (int t2 = 0; t2 < 4; t2++) {
      if (pofs[t2] >= 0) {
        uint4 d = *(const uint4*)(g2c + (size_t)pofs[t2] + eoff);
        f32x2 f;
        f = __builtin_amdgcn_cvt_pk_f32_fp8(d.x, false); s[0] += f[0]; s[1] += f[1];
        f = __builtin_amdgcn_cvt_pk_f32_fp8(d.x, true);  s[2] += f[0]; s[3] += f[1];
        f = __builtin_amdgcn_cvt_pk_f32_fp8(d.y, false); s[4] += f[0]; s[5] += f[1];
        f = __builtin_amdgcn_cvt_pk_f32_fp8(d.y, true);  s[6] += f[0]; s[7] += f[1];
        f = __builtin_amdgcn_cvt_pk_f32_fp8(d.z, false); s[8] += f[0]; s[9] += f[1];
        f = __builtin_amdgcn_cvt_pk_f32_fp8(d.z, true);  s[10] += f[0]; s[11] += f[1];
        f = __builtin_amdgcn_cvt_pk_f32_fp8(d.w, false); s[12] += f[0]; s[13] += f[1];
        f = __builtin_amdgcn_cvt_pk_f32_fp8(d.w, true);  s[14] += f[0]; s[15] += f[1];
      }
    }
  }

#pragma unroll
  for (int q = 0; q < 16; q++) s[q] += __shfl_xor(s[q], 8);

  if (half == 0) {
    s16x8 lo, hi;
    {
      const u16* sp = g2s + (size_t)dst * 128 + eoff;
      lo = *(const s16x8*)sp;
      hi = *(const s16x8*)(sp + 8);
    }
    float* op = out + (size_t)dst * DD + eoff;
#pragma unroll
    for (int q = 0; q < 8; q++) {
      float v = s[q] * 0.015625f + bf2f(lo[q]) + b2[eoff + q];
      op[q] = 1.f / (1.f + expf(10.f - v));
    }
#pragma unroll
    for (int q = 0; q < 8; q++) {
      float v = s[q + 8] * 0.015625f + bf2f(hi[q]) + b2[eoff + 8 + q];
      op[q + 8] = 1.f / (1.f + expf(10.f - v));
    }
  }
}

// ---------------- launch ----------------

extern "C" void kernel_launch(void* const* d_in, const int* in_sizes, int n_in,
                              void* d_out, int out_size, void* d_ws, size_t ws_size,
                              hipStream_t stream) {
  const float* x   = (const float*)d_in[0];
  const int*   ei  = (const int*)d_in[1];
  const int*   ec  = (const int*)d_in[2];
  const float* Ws1 = (const float*)d_in[3];
  const float* b1  = (const float*)d_in[4];
  const float* Ws2 = (const float*)d_in[5];
  const float* b2  = (const float*)d_in[6];
  const float* Wc1 = (const float*)d_in[7];
  const float* Wc2 = (const float*)d_in[8];
  float* out = (float*)d_out;

  char* p = (char*)d_ws;
  // g2c fp8 [N,1024] (51.2MB) aliases aggf8 (51.2MB): aggf8 dead by gemm2g.
  u8*   g2c    = (u8*)p;
  u8*   aggf8  = (u8*)p;                          // [C*N,128] fp8
  u16*  g2s    = (u16*)(p + 51200000);            // [N,128] bf16 (12.8MB)
  u16*  xb     = (u16*)(p + 64000000);            // [N,128] bf16 (12.8MB)
  u16*  hb     = (u16*)(p + 76800000);            // [N,256] bf16 (25.6MB)
  unsigned* W1c8 = (unsigned*)(p + 102400000);    // 256KB fp8 frag-major
  u16*  W1s    = (u16*)(p + 102662144);           // 64KB bf16 frag-major
  u16*  W2f    = (u16*)(p + 102727680);           // 576KB bf16 frag-major
  int2* oc     = (int2*)(p + 103317504);          // [N*C] {off,cnt}
  int*  sv     = (int*)(p + 106517504);           // [E] src*8+c
  int*  counts = (int*)(p + 109717504);           // [N*C]
  int*  gcount = (int*)(p + 111317504);
  int*  cursor = (int*)(p + 111317760);           // [N*C]
  u8*   xf8    = (u8*)(p + 112917760);            // [N,128] fp8 (6.4MB)

  hipMemsetAsync(counts, 0, 1600256, stream);     // counts + gcount

  k_prep<<<7786, 256, 0, stream>>>(x, xb, xf8, Wc1, W1c8, Ws1, W1s,
                                   Wc2, Ws2, W2f, ei, ec, counts);
  k_offsets<<<1563, 256, 0, stream>>>(counts, oc, cursor, gcount);
  k_fill<<<3125, 256, 0, stream>>>(ei, ec, cursor, sv);

  k_agg1<<<3125, 256, 0, stream>>>(xf8, oc, sv, aggf8);
  k_gemm1s<<<dim3(2, 782), 256, 0, stream>>>(xb, aggf8, W1c8, W1s, b1, hb);
  k_gemm2g<<<782, 256, 0, stream>>>(hb, W2f, g2c, g2s);
  k_final<<<3125, 256, 0, stream>>>(g2c, g2s, b2, oc, sv, out);
}

// Round 35
// 284.213 us; speedup vs baseline: 1.0373x; 1.0011x over previous
//
#include <hip/hip_runtime.h>

// GNN: 2-layer edge-coloured conv on MI355X.
// Round 35: k_gemm1s A-prefetch deepened to 2 phases ahead (3 rotating
// register buffers) — one phase (~150-400cyc) can't cover ~900cyc HBM
// latency; two can. Everything else = round 34 (passed, 284.5us).

#define NN 50000
#define EE 800000
#define DD 128
#define HH 256
#define CC 8

typedef unsigned short u16;
typedef unsigned char u8;
typedef unsigned long long u64;
typedef __attribute__((ext_vector_type(8))) short s16x8;
typedef __attribute__((ext_vector_type(4))) float f32x4;
typedef __attribute__((ext_vector_type(2))) float f32x2;

__device__ __forceinline__ float bf2f(short u) {
  return __uint_as_float(((unsigned)(u16)u) << 16);
}
__device__ __forceinline__ u16 f2bf(float f) {
  unsigned u = __float_as_uint(f);
  u = (u + 0x7FFFu + ((u >> 16) & 1u)) >> 16;   // RNE
  return (u16)u;
}

// ---------------- fused prep: castx | wt1c8 | wt1s | wt2f | hist ----------

__global__ void __launch_bounds__(256) k_prep(
    const float* __restrict__ x, u16* __restrict__ xb, u8* __restrict__ xf8,
    const float* __restrict__ Wc1, unsigned* __restrict__ W1c8,
    const float* __restrict__ Ws1, u16* __restrict__ W1s,
    const float* __restrict__ Wc2, const float* __restrict__ Ws2,
    u16* __restrict__ W2f,
    const int* __restrict__ ei, const int* __restrict__ ec,
    int* __restrict__ counts) {
  int b = blockIdx.x;
  int tid = threadIdx.x;
  if (b < 3125) {
    int i = b * 256 + tid;
    const float4* xp = (const float4*)x + (size_t)i * 2;
    float4 a = xp[0], bb = xp[1];
    s16x8 r;
    r[0] = f2bf(a.x); r[1] = f2bf(a.y); r[2] = f2bf(a.z); r[3] = f2bf(a.w);
    r[4] = f2bf(bb.x); r[5] = f2bf(bb.y); r[6] = f2bf(bb.z); r[7] = f2bf(bb.w);
    *(s16x8*)(xb + (size_t)i * 8) = r;
    unsigned p0 = __builtin_amdgcn_cvt_pk_fp8_f32(a.x, a.y, 0, false);
    p0 = __builtin_amdgcn_cvt_pk_fp8_f32(a.z, a.w, p0, true);
    unsigned p1 = __builtin_amdgcn_cvt_pk_fp8_f32(bb.x, bb.y, 0, false);
    p1 = __builtin_amdgcn_cvt_pk_fp8_f32(bb.z, bb.w, p1, true);
    *(uint2*)(xf8 + (size_t)i * 8) = make_uint2(p0, p1);
  } else if (b < 3381) {
    int t = (b - 3125) * 256 + tid;
    int half = t & 1;
    int slot = t >> 1;
    int lane = slot & 63;
    int sk = slot >> 6;
    int kkg = sk & 31, col16 = sk >> 5;
    int col = col16 * 16 + (lane & 15);
    int kb = kkg * 32 + (lane >> 4) * 8 + half * 4;
    int c = kb >> 7, f = kb & 127;
    const float* wp = Wc1 + (size_t)c * (HH * DD) + col * DD + f;
    unsigned r = __builtin_amdgcn_cvt_pk_fp8_f32(wp[0] * 256.f, wp[1] * 256.f, 0, false);
    r = __builtin_amdgcn_cvt_pk_fp8_f32(wp[2] * 256.f, wp[3] * 256.f, r, true);
    W1c8[t] = r;
  } else if (b < 3509) {
    int i = (b - 3381) * 256 + tid;
    int e = i & 7;
    int slot = i >> 3;
    int lane = slot & 63;
    int sk = slot >> 6;
    int kk = sk & 3, col16 = sk >> 2;
    int col = col16 * 16 + (lane & 15);
    int k = kk * 32 + (lane >> 4) * 8 + e;
    W1s[i] = f2bf(Ws1[col * DD + k]);
  } else if (b < 4661) {
    int i = (b - 3509) * 256 + tid;
    if (i < 294912) {
      int e = i & 7;
      int t = i >> 3;
      int rs = t & 15; t >>= 4;
      int kg = t & 3;  t >>= 2;
      int kk = t & 7;
      int col16 = t >> 3;
      int oc2 = col16 * 16 + rs;
      int c = oc2 >> 7, o = oc2 & 127;
      int k = kk * 32 + kg * 8 + e;
      float v = (c < CC) ? Wc2[c * (DD * HH) + o * HH + k] * 64.f
                         : Ws2[o * HH + k];
      W2f[i] = f2bf(v);
    }
  } else {
    int e = (b - 4661) * 256 + tid;
    if (e < EE) {
      int dst = ei[EE + e];
      int c = ec[e];
      atomicAdd(&counts[dst * CC + c], 1);
    }
  }
}

// ---------------- CSR build over seg = dst*8 + c ----------------

__global__ void k_offsets(const int* __restrict__ counts, int2* __restrict__ oc,
                          int* __restrict__ cursor, int* __restrict__ gcount) {
  __shared__ int lds[256];
  __shared__ int basesh;
  int tid = threadIdx.x;
  int i = blockIdx.x * 256 + tid;
  int c = (i < CC * NN) ? counts[i] : 0;
  lds[tid] = c;
  __syncthreads();
  int v = c;
  for (int s = 1; s < 256; s <<= 1) {
    int t = (tid >= s) ? lds[tid - s] : 0;
    __syncthreads();
    v += t;
    lds[tid] = v;
    __syncthreads();
  }
  if (tid == 255) basesh = atomicAdd(gcount, v);
  __syncthreads();
  int excl = basesh + v - c;
  if (i < CC * NN) {
    oc[i] = make_int2(excl, c);
    cursor[i] = excl;
  }
}

__global__ void k_fill(const int* __restrict__ ei, const int* __restrict__ ec,
                       int* __restrict__ cursor, int* __restrict__ sv) {
  int e = blockIdx.x * 256 + threadIdx.x;
  if (e < EE) {
    int src = ei[e];
    int dst = ei[EE + e];
    int c = ec[e];
    int slot = atomicAdd(&cursor[dst * CC + c], 1);
    sv[slot] = src * 8 + c;
  }
}

// ---------------- layer 1: fp8 gather, colour-half split ----------------

__global__ void __launch_bounds__(256) k_agg1(
    const u8* __restrict__ xf8, const int2* __restrict__ oc,
    const int* __restrict__ sv, u8* __restrict__ aggf8) {
  int item = blockIdx.x * 256 + threadIdx.x;   // NN*16 exact
  int dst = item >> 4, t = item & 15;
  int ch = t & 7, chalf = t >> 3;
  int eoff = ch * 16;
#pragma unroll
  for (int cc = 0; cc < 4; ++cc) {
    int c = chalf * 4 + cc;
    int2 se = oc[dst * CC + c];
    float s[16];
#pragma unroll
    for (int q = 0; q < 16; q++) s[q] = 0.f;
    int j = 0;
    for (; j + 1 < se.y; j += 2) {
      int s0 = sv[se.x + j] >> 3;
      int s1 = sv[se.x + j + 1] >> 3;
      uint4 d0 = *(const uint4*)(xf8 + (size_t)s0 * 128 + eoff);
      uint4 d1 = *(const uint4*)(xf8 + (size_t)s1 * 128 + eoff);
      f32x2 f;
      f = __builtin_amdgcn_cvt_pk_f32_fp8(d0.x, false); s[0] += f[0]; s[1] += f[1];
      f = __builtin_amdgcn_cvt_pk_f32_fp8(d0.x, true);  s[2] += f[0]; s[3] += f[1];
      f = __builtin_amdgcn_cvt_pk_f32_fp8(d0.y, false); s[4] += f[0]; s[5] += f[1];
      f = __builtin_amdgcn_cvt_pk_f32_fp8(d0.y, true);  s[6] += f[0]; s[7] += f[1];
      f = __builtin_amdgcn_cvt_pk_f32_fp8(d0.z, false); s[8] += f[0]; s[9] += f[1];
      f = __builtin_amdgcn_cvt_pk_f32_fp8(d0.z, true);  s[10] += f[0]; s[11] += f[1];
      f = __builtin_amdgcn_cvt_pk_f32_fp8(d0.w, false); s[12] += f[0]; s[13] += f[1];
      f = __builtin_amdgcn_cvt_pk_f32_fp8(d0.w, true);  s[14] += f[0]; s[15] += f[1];
      f = __builtin_amdgcn_cvt_pk_f32_fp8(d1.x, false); s[0] += f[0]; s[1] += f[1];
      f = __builtin_amdgcn_cvt_pk_f32_fp8(d1.x, true);  s[2] += f[0]; s[3] += f[1];
      f = __builtin_amdgcn_cvt_pk_f32_fp8(d1.y, false); s[4] += f[0]; s[5] += f[1];
      f = __builtin_amdgcn_cvt_pk_f32_fp8(d1.y, true);  s[6] += f[0]; s[7] += f[1];
      f = __builtin_amdgcn_cvt_pk_f32_fp8(d1.z, false); s[8] += f[0]; s[9] += f[1];
      f = __builtin_amdgcn_cvt_pk_f32_fp8(d1.z, true);  s[10] += f[0]; s[11] += f[1];
      f = __builtin_amdgcn_cvt_pk_f32_fp8(d1.w, false); s[12] += f[0]; s[13] += f[1];
      f = __builtin_amdgcn_cvt_pk_f32_fp8(d1.w, true);  s[14] += f[0]; s[15] += f[1];
    }
    if (j < se.y) {
      int s0 = sv[se.x + j] >> 3;
      uint4 d0 = *(const uint4*)(xf8 + (size_t)s0 * 128 + eoff);
      f32x2 f;
      f = __builtin_amdgcn_cvt_pk_f32_fp8(d0.x, false); s[0] += f[0]; s[1] += f[1];
      f = __builtin_amdgcn_cvt_pk_f32_fp8(d0.x, true);  s[2] += f[0]; s[3] += f[1];
      f = __builtin_amdgcn_cvt_pk_f32_fp8(d0.y, false); s[4] += f[0]; s[5] += f[1];
      f = __builtin_amdgcn_cvt_pk_f32_fp8(d0.y, true);  s[6] += f[0]; s[7] += f[1];
      f = __builtin_amdgcn_cvt_pk_f32_fp8(d0.z, false); s[8] += f[0]; s[9] += f[1];
      f = __builtin_amdgcn_cvt_pk_f32_fp8(d0.z, true);  s[10] += f[0]; s[11] += f[1];
      f = __builtin_amdgcn_cvt_pk_f32_fp8(d0.w, false); s[12] += f[0]; s[13] += f[1];
      f = __builtin_amdgcn_cvt_pk_f32_fp8(d0.w, true);  s[14] += f[0]; s[15] += f[1];
    }
    unsigned r0 = __builtin_amdgcn_cvt_pk_fp8_f32(s[0], s[1], 0, false);
    r0 = __builtin_amdgcn_cvt_pk_fp8_f32(s[2], s[3], r0, true);
    unsigned r1 = __builtin_amdgcn_cvt_pk_fp8_f32(s[4], s[5], 0, false);
    r1 = __builtin_amdgcn_cvt_pk_fp8_f32(s[6], s[7], r1, true);
    unsigned r2 = __builtin_amdgcn_cvt_pk_fp8_f32(s[8], s[9], 0, false);
    r2 = __builtin_amdgcn_cvt_pk_fp8_f32(s[10], s[11], r2, true);
    unsigned r3 = __builtin_amdgcn_cvt_pk_fp8_f32(s[12], s[13], 0, false);
    r3 = __builtin_amdgcn_cvt_pk_fp8_f32(s[14], s[15], r3, true);
    *(uint4*)(aggf8 + ((size_t)c * NN + dst) * 128 + eoff) =
        make_uint4(r0, r1, r2, r3);
  }
}

// ---------------- layer 1 dense: 64-row blocks, 2-deep A prefetch ----------

#define LOADA8(af, p) do {                                                     \
  _Pragma("unroll") for (int kk = 0; kk < 4; ++kk)                             \
    af[kk] = *(const u64*)(aggf8 + ((size_t)(p) * NN + rowA) * 128 +           \
                           kk * 32 + kg * 8);                                  \
  } while (0)

#define LOADAS(af) do {                                                        \
  _Pragma("unroll") for (int kk = 0; kk < 4; ++kk)                             \
    af[kk] = *(const s16x8*)(xb + (size_t)rowA * DD + kk * 32 + kg * 8);       \
  } while (0)

#define STAGE8(p, buf) do {                                                    \
  _Pragma("unroll") for (int i2 = 0; i2 < 4; ++i2) {                           \
    int fc = i2 * 2 + (w >> 1);                                                \
    int kb2 = (w & 1) * 2;                                                     \
    const char* gs = (const char*)W1c8 +                                       \
        (((ch * 8 + fc) * 32 + (p) * 4 + kb2) << 9) + lane * 16;               \
    char* lp = Bs + (buf) * 16384 + ((fc * 4 + kb2) << 9);                     \
    __builtin_amdgcn_global_load_lds(                                          \
        (const __attribute__((address_space(1))) void*)gs,                     \
        (__attribute__((address_space(3))) void*)lp, 16, 0, 0);                \
  } } while (0)

#define MFMA8(af, buf) do {                                                    \
  _Pragma("unroll") for (int kk = 0; kk < 4; ++kk)                             \
  _Pragma("unroll") for (int fc = 0; fc < 8; ++fc) {                           \
    long bfr = *(const long*)(Bs + (buf) * 16384 + ((fc * 4 + kk) << 9) +      \
                              lane * 8);                                       \
    acc[fc] = __builtin_amdgcn_mfma_f32_16x16x32_fp8_fp8(                      \
        (long)af[kk], bfr, acc[fc], 0, 0, 0);                                  \
  } } while (0)

#define MFMASG(af) do {                                                        \
  _Pragma("unroll") for (int kk = 0; kk < 4; ++kk)                             \
  _Pragma("unroll") for (int fc = 0; fc < 8; ++fc) {                           \
    s16x8 bfr = *(const s16x8*)(W1s +                                          \
        ((((ch * 8 + fc) * 4 + kk) << 6) + lane) * 8);                         \
    acc[fc] = __builtin_amdgcn_mfma_f32_16x16x32_bf16(af[kk], bfr,             \
                                                      acc[fc], 0, 0, 0);       \
  } } while (0)

__global__ void __launch_bounds__(256, 5) k_gemm1s(
    const u16* __restrict__ xb, const u8* __restrict__ aggf8,
    const unsigned* __restrict__ W1c8, const u16* __restrict__ W1s,
    const float* __restrict__ b1, u16* __restrict__ hb) {
  __shared__ char Bs[32768];              // 2 x 16KB fp8 double buffer
  int ch = blockIdx.x;                    // 0..1
  int rb = blockIdx.y;                    // 0..781
  int tid = threadIdx.x;
  int w = tid >> 6, lane = tid & 63;
  int rs = lane & 15, kg = lane >> 4;
  int r0 = rb * 64 + w * 16;

  int rowA = min(r0 + rs, NN - 1);

  f32x4 acc[8];
#pragma unroll
  for (int i = 0; i < 8; i++)
#pragma unroll
    for (int q = 0; q < 4; q++) acc[i][q] = 0.f;

  u64 afA[4], afB[4], afC[4];             // rotating, prefetch distance 2
  s16x8 afS[4];
  STAGE8(0, 0);
  LOADA8(afA, 0);
  LOADA8(afB, 1);
  __syncthreads();

#pragma unroll
  for (int ph = 0; ph < 8; ++ph) {        // 8 fp8 colour phases
    const int cb = ph & 1;
    if (ph < 7) STAGE8(ph + 1, cb ^ 1);
    if (ph + 2 < 8) {                     // prefetch A two phases ahead
      if (((ph + 2) % 3) == 0) { LOADA8(afA, ph + 2); }
      else if (((ph + 2) % 3) == 1) { LOADA8(afB, ph + 2); }
      else { LOADA8(afC, ph + 2); }
    } else if (ph + 2 == 8) {
      LOADAS(afS);                        // self A, 2 phases early
    }
    if ((ph % 3) == 0) { MFMA8(afA, cb); }
    else if ((ph % 3) == 1) { MFMA8(afB, cb); }
    else { MFMA8(afC, cb); }
    __syncthreads();
  }
#pragma unroll
  for (int i = 0; i < 8; i++)
#pragma unroll
    for (int q = 0; q < 4; q++) acc[i][q] *= 0.00390625f;
  MFMASG(afS);

#pragma unroll
  for (int fc = 0; fc < 8; ++fc) {
    int col = ch * 128 + fc * 16 + rs;
    float bias = b1[col];
#pragma unroll
    for (int q = 0; q < 4; ++q) {
      float v = acc[fc][q] + bias;
      if (v < 0.f) v = 0.f;
      int rr = r0 + kg * 4 + q;
      if (rr < NN) hb[(size_t)rr * HH + col] = f2bf(v);
    }
  }
}

// ---------------- layer 2 multiply-first: A-stationary, 64-row blocks -------

__global__ void __launch_bounds__(256, 3) k_gemm2g(
    const u16* __restrict__ hb, const u16* __restrict__ Wf,
    u8* __restrict__ g2c, u16* __restrict__ g2s) {
  __shared__ u16 Bs[24576];               // 48KB panel
  int rb = blockIdx.x;                    // 0..781
  int tid = threadIdx.x;
  int w = tid >> 6, lane = tid & 63;
  int rs = lane & 15, kg = lane >> 4;
  int r0 = rb * 64 + w * 16;

  int rowA = min(r0 + rs, NN - 1);

  s16x8 af[8];
#pragma unroll
  for (int kk = 0; kk < 8; ++kk)
    af[kk] = *(const s16x8*)(hb + (size_t)rowA * HH + kk * 32 + kg * 8);

  for (int cb = 0; cb < 12; ++cb) {
    {
      const char* src = (const char*)(Wf + (size_t)cb * 24576);
#pragma unroll
      for (int i = 0; i < 12; ++i) {
        const char* gs = src + ((i * 256 + w * 64 + lane) << 4);
        char* lp = (char*)Bs + ((i * 256 + w * 64) << 4);
        __builtin_amdgcn_global_load_lds(
            (const __attribute__((address_space(1))) void*)gs,
            (__attribute__((address_space(3))) void*)lp, 16, 0, 0);
      }
    }
    __syncthreads();

    int c16b = cb * 6;
    f32x4 acc[6];
#pragma unroll
    for (int i = 0; i < 6; i++)
#pragma unroll
      for (int q = 0; q < 4; q++) acc[i][q] = 0.f;

#pragma unroll
    for (int kk = 0; kk < 8; ++kk) {
#pragma unroll
      for (int fc = 0; fc < 6; ++fc) {
        s16x8 bfr = *(const s16x8*)(Bs + ((fc * 8 + kk) * 64 + lane) * 8);
        acc[fc] = __builtin_amdgcn_mfma_f32_16x16x32_bf16(af[kk], bfr, acc[fc], 0, 0, 0);
      }
    }

#pragma unroll
    for (int q = 0; q < 4; ++q) {
      int rr = r0 + kg * 4 + q;
      if (rr < NN) {
#pragma unroll
        for (int fc = 0; fc < 6; ++fc) {
          int col = (c16b + fc) * 16 + rs;
          if (col < 1024) {
            unsigned pk = __builtin_amdgcn_cvt_pk_fp8_f32(acc[fc][q],
                                                          acc[fc][q], 0, false);
            g2c[(size_t)rr * 1024 + col] = (u8)(pk & 0xFF);
          } else {
            g2s[(size_t)rr * 128 + (col - 1024)] = f2bf(acc[fc][q]);
          }
        }
      }
    }
    __syncthreads();
  }
}

// ---------------- layer 2 final: edge-half split gather + shfl combine ------

__global__ void __launch_bounds__(256) k_final(
    const u8* __restrict__ g2c, const u16* __restrict__ g2s,
    const float* __restrict__ b2,
    const int2* __restrict__ oc, const int* __restrict__ sv,
    float* __restrict__ out) {
  int item = blockIdx.x * 256 + threadIdx.x;   // NN*16 exact
  int dst = item >> 4, t = item & 15;
  int ch = t & 7, half = t >> 3;
  int eoff = ch * 16;

  int st, cn;
  {
    int2 a0 = oc[dst * CC];
    int2 a7 = oc[dst * CC + 7];
    st = a0.x;
    cn = a7.x + a7.y - a0.x;
  }

  float s[16];
#pragma unroll
  for (int q = 0; q < 16; q++) s[q] = 0.f;

  for (int j = half * 4; j < cn; j += 8) {
    int pofs[4];
#pragma unroll
    for (int t2 = 0; t2 < 4; t2++) {
      int jj = j + t2;
      if (jj < cn) {
        int v = sv[st + jj];
        pofs[t2] = (v >> 3) * 1024 + (v & 7) * 128;
      } else {
        pofs[t2] = -1;
      }
    }
#pragma unroll
    for (int t2 = 0; t2 < 4; t2++) {
      if (pofs[t2] >= 0) {
        uint4 d = *(const uint4*)(g2c + (size_t)pofs[t2] + eoff);
        f32x2 f;
        f = __builtin_amdgcn_cvt_pk_f32_fp8(d.x, false); s[0] += f[0]; s[1] += f[1];
        f = __builtin_amdgcn_cvt_pk_f32_fp8(d.x, true);  s[2] += f[0]; s[3] += f[1];
        f = __builtin_amdgcn_cvt_pk_f32_fp8(d.y, false); s[4] += f[0]; s[5] += f[1];
        f = __builtin_amdgcn_cvt_pk_f32_fp8(d.y, true);  s[6] += f[0]; s[7] += f[1];
        f = __builtin_amdgcn_cvt_pk_f32_fp8(d.z, false); s[8] += f[0]; s[9] += f[1];
        f = __builtin_amdgcn_cvt_pk_f32_fp8(d.z, true);  s[10] += f[0]; s[11] += f[1];
        f = __builtin_amdgcn_cvt_pk_f32_fp8(d.w, false); s[12] += f[0]; s[13] += f[1];
        f = __builtin_amdgcn_cvt_pk_f32_fp8(d.w, true);  s[14] += f[0]; s[15] += f[1];
      }
    }
  }

#pragma unroll
  for (int q = 0; q < 16; q++) s[q] += __shfl_xor(s[q], 8);

  if (half == 0) {
    s16x8 lo, hi;
    {
      const u16* sp = g2s + (size_t)dst * 128 + eoff;
      lo = *(const s16x8*)sp;
      hi = *(const s16x8*)(sp + 8);
    }
    float* op = out + (size_t)dst * DD + eoff;
#pragma unroll
    for (int q = 0; q < 8; q++) {
      float v = s[q] * 0.015625f + bf2f(lo[q]) + b2[eoff + q];
      op[q] = 1.f / (1.f + expf(10.f - v));
    }
#pragma unroll
    for (int q = 0; q < 8; q++) {
      float v = s[q + 8] * 0.015625f + bf2f(hi[q]) + b2[eoff + 8 + q];
      op[q + 8] = 1.f / (1.f + expf(10.f - v));
    }
  }
}

// ---------------- launch ----------------

extern "C" void kernel_launch(void* const* d_in, const int* in_sizes, int n_in,
                              void* d_out, int out_size, void* d_ws, size_t ws_size,
                              hipStream_t stream) {
  const float* x   = (const float*)d_in[0];
  const int*   ei  = (const int*)d_in[1];
  const int*   ec  = (const int*)d_in[2];
  const float* Ws1 = (const float*)d_in[3];
  const float* b1  = (const float*)d_in[4];
  const float* Ws2 = (const float*)d_in[5];
  const float* b2  = (const float*)d_in[6];
  const float* Wc1 = (const float*)d_in[7];
  const float* Wc2 = (const float*)d_in[8];
  float* out = (float*)d_out;

  char* p = (char*)d_ws;
  // g2c fp8 [N,1024] (51.2MB) aliases aggf8 (51.2MB): aggf8 dead by gemm2g.
  u8*   g2c    = (u8*)p;
  u8*   aggf8  = (u8*)p;                          // [C*N,128] fp8
  u16*  g2s    = (u16*)(p + 51200000);            // [N,128] bf16 (12.8MB)
  u16*  xb     = (u16*)(p + 64000000);            // [N,128] bf16 (12.8MB)
  u16*  hb     = (u16*)(p + 76800000);            // [N,256] bf16 (25.6MB)
  unsigned* W1c8 = (unsigned*)(p + 102400000);    // 256KB fp8 frag-major
  u16*  W1s    = (u16*)(p + 102662144);           // 64KB bf16 frag-major
  u16*  W2f    = (u16*)(p + 102727680);           // 576KB bf16 frag-major
  int2* oc     = (int2*)(p + 103317504);          // [N*C] {off,cnt}
  int*  sv     = (int*)(p + 106517504);           // [E] src*8+c
  int*  counts = (int*)(p + 109717504);           // [N*C]
  int*  gcount = (int*)(p + 111317504);
  int*  cursor = (int*)(p + 111317760);           // [N*C]
  u8*   xf8    = (u8*)(p + 112917760);            // [N,128] fp8 (6.4MB)

  hipMemsetAsync(counts, 0, 1600256, stream);     // counts + gcount

  k_prep<<<7786, 256, 0, stream>>>(x, xb, xf8, Wc1, W1c8, Ws1, W1s,
                                   Wc2, Ws2, W2f, ei, ec, counts);
  k_offsets<<<1563, 256, 0, stream>>>(counts, oc, cursor, gcount);
  k_fill<<<3125, 256, 0, stream>>>(ei, ec, cursor, sv);

  k_agg1<<<3125, 256, 0, stream>>>(xf8, oc, sv, aggf8);
  k_gemm1s<<<dim3(2, 782), 256, 0, stream>>>(xb, aggf8, W1c8, W1s, b1, hb);
  k_gemm2g<<<782, 256, 0, stream>>>(hb, W2f, g2c, g2s);
  k_final<<<3125, 256, 0, stream>>>(g2c, g2s, b2, oc, sv, out);
}